// Round 4
// baseline (437.755 us; speedup 1.0000x reference)
//
#include <hip/hip_runtime.h>

typedef float f32x4 __attribute__((ext_vector_type(4)));
typedef short s16x8 __attribute__((ext_vector_type(8)));

#define NN 4096
#define NB 32
#define DIN 64
#define DH 128
#define DOUT 32
#define DIM 40

__device__ __forceinline__ unsigned short f2bf(float f) {
    unsigned int u = __float_as_uint(f);
    unsigned int r = (u + 0x7FFFu + ((u >> 16) & 1u)) >> 16;
    return (unsigned short)r;
}
__device__ __forceinline__ float bf2f(unsigned short h) {
    return __uint_as_float(((unsigned int)h) << 16);
}
__device__ __forceinline__ void gload16(const void* g, void* l) {
    __builtin_amdgcn_global_load_lds(
        (const __attribute__((address_space(1))) unsigned int*)g,
        (__attribute__((address_space(3))) unsigned int*)l, 16, 0, 0);
}
__device__ __forceinline__ void bar() {
    asm volatile("" ::: "memory");
    __builtin_amdgcn_s_barrier();
    asm volatile("" ::: "memory");
}

// ---------------- stage 1: n1/n2 = tanh(3*(emb @ W + b)) ----------------
__global__ __launch_bounds__(256) void k_embed(
    const float* __restrict__ emb1, const float* __restrict__ emb2,
    const float* __restrict__ l1w, const float* __restrict__ l1b,
    const float* __restrict__ l2w, const float* __restrict__ l2b,
    float* __restrict__ n1, float* __restrict__ n2)
{
    __shared__ float w1s[DIM * DIM], w2s[DIM * DIM], b1s[DIM], b2s[DIM];
    int tid = threadIdx.x;
    for (int i = tid; i < DIM * DIM; i += 256) { w1s[i] = l1w[i]; w2s[i] = l2w[i]; }
    if (tid < DIM) { b1s[tid] = l1b[tid]; b2s[tid] = l2b[tid]; }
    __syncthreads();
    int t = blockIdx.x * 256 + tid;          // < 2*4096*40 = 327680
    int half = t >= NN * DIM;
    int r = t - half * (NN * DIM);
    int i = r / DIM, c = r - i * DIM;
    const float* emb = half ? emb2 : emb1;
    const float* ws  = half ? w2s : w1s;
    float acc = half ? b2s[c] : b1s[c];
    for (int k = 0; k < DIM; k++) acc += emb[i * DIM + k] * ws[k * DIM + c];
    (half ? n2 : n1)[r] = tanhf(3.0f * acc);
}

// ---------------- stage 2: adjacency bits + degree (register-tiled) ----------------
#define APAD 44
#define TPAD 69
__global__ __launch_bounds__(256) void k_adj2(
    const float* __restrict__ n1, const float* __restrict__ n2,
    unsigned int* __restrict__ mtb, int* __restrict__ deg)
{
    const int bi = blockIdx.x, bj = blockIdx.y;
    if (bj < bi) return;
    const bool diag = (bi == bj);
    const int i0 = bi * 64, j0 = bj * 64;

    __shared__ __align__(16) float n1i[64 * APAD], n1j[64 * APAD];
    __shared__ __align__(16) float n2iT[DIM * 64], n2jT[DIM * 64];
    __shared__ float T1[64 * TPAD], T2[64 * TPAD];

    const int tid = threadIdx.x;
    for (int idx = tid; idx < 64 * DIM; idx += 256) {
        int r = idx / DIM, c = idx - r * DIM;
        n1i[r * APAD + c] = n1[(i0 + r) * DIM + c];
        n1j[r * APAD + c] = n1[(j0 + r) * DIM + c];
    }
    for (int idx = tid; idx < DIM * 64; idx += 256) {
        int k = idx >> 6, col = idx & 63;
        n2iT[k * 64 + col] = n2[(i0 + col) * DIM + k];
        n2jT[k * 64 + col] = n2[(j0 + col) * DIM + k];
    }
    __syncthreads();

    const int tq = tid & 15, tp = tid >> 4;
    const int rowb = tp * 4, colb = tq * 4;
    f32x4 acc1[4] = {}, acc2[4] = {};
    for (int k4 = 0; k4 < DIM; k4 += 4) {
        f32x4 a1[4], a2[4];
        #pragma unroll
        for (int di = 0; di < 4; di++) {
            a1[di] = *(const f32x4*)&n1i[(rowb + di) * APAD + k4];
            a2[di] = *(const f32x4*)&n1j[(rowb + di) * APAD + k4];
        }
        #pragma unroll
        for (int kk = 0; kk < 4; kk++) {
            f32x4 b2 = *(const f32x4*)&n2jT[(k4 + kk) * 64 + colb];
            f32x4 b1 = *(const f32x4*)&n2iT[(k4 + kk) * 64 + colb];
            #pragma unroll
            for (int di = 0; di < 4; di++) {
                acc1[di] += a1[di][kk] * b2;   // T1[p][q] = n1[I]·n2[J]
                acc2[di] += a2[di][kk] * b1;   // T2[p][q] = n1[J]·n2[I]
            }
        }
    }
    #pragma unroll
    for (int di = 0; di < 4; di++)
        #pragma unroll
        for (int dq = 0; dq < 4; dq++) {
            T1[(rowb + di) * TPAD + colb + dq] = acc1[di][dq];
            T2[(rowb + di) * TPAD + colb + dq] = acc2[di][dq];
        }
    __syncthreads();

    const int lane = tid & 63, w = tid >> 6;
    const int p = lane;
    #pragma unroll
    for (int qq = 0; qq < 16; qq++) {
        int q = w * 16 + qq;
        float t1  = T1[p * TPAD + q];
        float t2b = T2[q * TPAD + p];
        bool bit = (t1 > t2b) || (diag && p == q);
        unsigned long long mask = __ballot(bit);
        if (lane == 0) {
            mtb[(size_t)(j0 + q) * 128 + (i0 >> 5)]     = (unsigned int)mask;
            mtb[(size_t)(j0 + q) * 128 + (i0 >> 5) + 1] = (unsigned int)(mask >> 32);
            atomicAdd(&deg[j0 + q], (int)__popcll(mask));
        }
        if (!diag) {
            float t2  = T2[p * TPAD + q];
            float t1b = T1[q * TPAD + p];
            unsigned long long m2 = __ballot(t2 > t1b);
            if (lane == 0) {
                mtb[(size_t)(i0 + q) * 128 + (j0 >> 5)]     = (unsigned int)m2;
                mtb[(size_t)(i0 + q) * 128 + (j0 >> 5) + 1] = (unsigned int)(m2 >> 32);
                atomicAdd(&deg[i0 + q], (int)__popcll(m2));
            }
        }
    }
}

__global__ void k_dinv(const int* __restrict__ deg, float* __restrict__ dinv) {
    int i = blockIdx.x * 256 + threadIdx.x;
    if (i < NN) dinv[i] = 1.0f / sqrtf((float)deg[i]);
}

// bits -> bf16 0/1 matrix MT[j][i]
__global__ __launch_bounds__(256) void k_expand(
    const unsigned int* __restrict__ mtb, unsigned short* __restrict__ MT)
{
    int idx = blockIdx.x * 256 + threadIdx.x;   // < 4096*128
    unsigned int bits = mtb[idx];
    size_t base = (size_t)idx * 32;
    #pragma unroll
    for (int q = 0; q < 4; q++) {
        s16x8 v;
        #pragma unroll
        for (int e = 0; e < 8; e++)
            v[e] = (short)(((bits >> (q * 8 + e)) & 1u) ? 0x3F80 : 0);
        *(s16x8*)(MT + base + q * 8) = v;
    }
}

// ---------------- YT[c=b*128+f][i] = bf16( dinv_i * (x[b,i,:] @ W1[:,f]) ) ----------------
__global__ __launch_bounds__(256) void k_y1(
    const float* __restrict__ x, const float* __restrict__ W1,
    const float* __restrict__ dinv, unsigned short* __restrict__ YT)
{
    __shared__ __align__(16) float xs[128][DIN];
    __shared__ __align__(16) float w1s[DIN][DH];
    int i0 = blockIdx.x * 128, b = blockIdx.y;
    int tid = threadIdx.x;
    const f32x4* xg = (const f32x4*)(x + ((size_t)(b * NN + i0)) * DIN);
    #pragma unroll
    for (int q = 0; q < 8; q++) {
        int idx = q * 256 + tid;
        int row = idx >> 4, c4 = idx & 15;
        *(f32x4*)&xs[row][c4 * 4] = xg[(size_t)row * 16 + c4];
    }
    #pragma unroll
    for (int q = 0; q < 8; q++) {
        int idx = q * 256 + tid;
        int row = idx >> 5, c4 = idx & 31;
        *(f32x4*)&w1s[row][c4 * 4] = ((const f32x4*)W1)[idx];
    }
    __syncthreads();
    int tf = tid & 15, ti = tid >> 4;
    f32x4 t0[8] = {}, t1[8] = {};
    for (int k4 = 0; k4 < DIN; k4 += 4) {
        f32x4 xv[8];
        #pragma unroll
        for (int ii = 0; ii < 8; ii++) xv[ii] = *(const f32x4*)&xs[ti * 8 + ii][k4];
        #pragma unroll
        for (int kk = 0; kk < 4; kk++) {
            f32x4 w0 = *(const f32x4*)&w1s[k4 + kk][tf * 8];
            f32x4 w1v = *(const f32x4*)&w1s[k4 + kk][tf * 8 + 4];
            #pragma unroll
            for (int ii = 0; ii < 8; ii++) {
                float s = xv[ii][kk];
                t0[ii] += s * w0;
                t1[ii] += s * w1v;
            }
        }
    }
    float dvv[8];
    #pragma unroll
    for (int ii = 0; ii < 8; ii++) dvv[ii] = dinv[i0 + ti * 8 + ii];
    #pragma unroll
    for (int ff = 0; ff < 8; ff++) {
        s16x8 pk;
        #pragma unroll
        for (int ii = 0; ii < 8; ii++) {
            float v = (ff < 4 ? t0[ii][ff] : t1[ii][ff - 4]) * dvv[ii];
            pk[ii] = (short)f2bf(v);
        }
        *(s16x8*)(YT + ((size_t)(b * DH + tf * 8 + ff)) * NN + i0 + ti * 8) = pk;
    }
}

// ======== gemm1: 256x256 tile, BK=64, 8 waves, balanced-phase counted-vmcnt ========
// Per K-tile: 4 phases (ks0.lo, ks1.lo, ks0.hi, ks1.hi), reads 8/8/4/4.
// Stages during tile t: P0 -> B(t+1)h1 [buf^1], P1 -> A(t+1)h0 [buf^1],
// P2 -> A(t+1)h1 [buf^1], P3 -> B(t+2)h0 [buf, deep; legal: bf reads issued P0/P1].
__global__ __launch_bounds__(512, 2) void gemm8(
    const unsigned short* __restrict__ A, const unsigned short* __restrict__ Bt,
    unsigned short* __restrict__ H, const float* __restrict__ dinv,
    const float* __restrict__ bias)
{
    constexpr int K = NN;          // 4096
    constexpr int NT = K / 64;     // 64 K-tiles
    __shared__ __align__(16) unsigned short As[2][256 * 64];   // 64 KB
    __shared__ __align__(16) unsigned short Bs[2][256 * 64];   // 64 KB

    const int tid = threadIdx.x;
    const int lane = tid & 63;
    const int w = tid >> 6;                 // wave 0..7
    const int wm = w >> 2, wn = w & 3;      // 2 x 4 wave grid
    const int fr = lane & 15, kg = lane >> 4;

    const int bid = blockIdx.x;             // 256 blocks -> XCD swizzle
    const int swz = (bid & 7) * 32 + (bid >> 3);
    const int bx = swz & 15, by = swz >> 4;
    const int c0 = bx * 256, j0 = by * 256;

    const int cid0 = w * 128 + lane, cid1 = cid0 + 64;
    const int r0 = cid0 >> 3, k0c = cid0 & 7;
    const int r1 = cid1 >> 3, k1c = cid1 & 7;
    const int so0 = r0 * K + ((k0c ^ (r0 & 7)) << 3);   // ushort units
    const int so1 = r1 * K + ((k1c ^ (r1 & 7)) << 3);
    const int lb0 = (w * 2 + 0) * 512;                  // ushort units
    const int lb1 = (w * 2 + 1) * 512;

    const unsigned short* Aj = A + (size_t)j0 * K;
    const unsigned short* Bc = Bt + (size_t)c0 * K;

#define STAGE_A(buf, half, kt) do { \
    const unsigned short* g_ = Aj + (size_t)((half) * 128) * K + (kt); \
    gload16(g_ + so0, &As[buf][(half) * 8192 + lb0]); \
    gload16(g_ + so1, &As[buf][(half) * 8192 + lb1]); } while (0)
#define STAGE_B(buf, half, kt) do { \
    const unsigned short* g_ = Bc + (size_t)((half) * 128) * K + (kt); \
    gload16(g_ + so0, &Bs[buf][(half) * 8192 + lb0]); \
    gload16(g_ + so1, &Bs[buf][(half) * 8192 + lb1]); } while (0)

    // prologue: tile0 complete (8 loads) + deep B(1)h0 (2 loads)
    STAGE_A(0, 0, 0);  STAGE_A(0, 1, 0);
    STAGE_B(0, 0, 0);  STAGE_B(0, 1, 0);
    STAGE_B(1, 0, 64);
    asm volatile("s_waitcnt vmcnt(2)" ::: "memory");   // tile0 landed
    bar();

    const int x0 = ((kg) ^ (fr & 7)) << 4;        // ks0 chunk, bytes
    const int x1 = ((4 + kg) ^ (fr & 7)) << 4;    // ks1 chunk, bytes
    int aOff[8], bOff[4];
    #pragma unroll
    for (int m = 0; m < 8; m++) aOff[m] = (wm * 128 + m * 16 + fr) * 128;
    #pragma unroll
    for (int n = 0; n < 4; n++) bOff[n] = (wn * 64 + n * 16 + fr) * 128;

    f32x4 acc[8][4] = {};

    for (int t = 0; t < NT; t++) {
        const int b = t & 1;
        const char* Ab = (const char*)As[b];
        const char* Bb = (const char*)Bs[b];
        const int kt1 = (t + 1) * 64, kt2 = (t + 2) * 64;
        const bool s1 = (t + 1) < NT, s2 = (t + 2) < NT;
        s16x8 a0[4], a1[4], b0[4], b1[4];

        // ---- P0: reads ks0.lo A + ks0 B (8); stage B(t+1)h1; mfma ks0 m0-3
        #pragma unroll
        for (int m = 0; m < 4; m++) a0[m] = *(const s16x8*)(Ab + aOff[m] + x0);
        #pragma unroll
        for (int n = 0; n < 4; n++) b0[n] = *(const s16x8*)(Bb + bOff[n] + x0);
        if (s1) STAGE_B(b ^ 1, 1, kt1);
        bar();
        __builtin_amdgcn_s_setprio(1);
        #pragma unroll
        for (int m = 0; m < 4; m++)
            #pragma unroll
            for (int n = 0; n < 4; n++)
                acc[m][n] = __builtin_amdgcn_mfma_f32_16x16x32_bf16(a0[m], b0[n], acc[m][n], 0, 0, 0);
        __builtin_amdgcn_s_setprio(0);
        bar();

        // ---- P1: reads ks1.lo A + ks1 B (8); stage A(t+1)h0; mfma ks1 m0-3
        #pragma unroll
        for (int m = 0; m < 4; m++) a1[m] = *(const s16x8*)(Ab + aOff[m] + x1);
        #pragma unroll
        for (int n = 0; n < 4; n++) b1[n] = *(const s16x8*)(Bb + bOff[n] + x1);
        if (s1) STAGE_A(b ^ 1, 0, kt1);
        bar();
        __builtin_amdgcn_s_setprio(1);
        #pragma unroll
        for (int m = 0; m < 4; m++)
            #pragma unroll
            for (int n = 0; n < 4; n++)
                acc[m][n] = __builtin_amdgcn_mfma_f32_16x16x32_bf16(a1[m], b1[n], acc[m][n], 0, 0, 0);
        __builtin_amdgcn_s_setprio(0);
        bar();

        // ---- P2: reads ks0.hi A (4); stage A(t+1)h1; mfma ks0 m4-7
        #pragma unroll
        for (int m = 0; m < 4; m++) a0[m] = *(const s16x8*)(Ab + aOff[m + 4] + x0);
        if (s1) STAGE_A(b ^ 1, 1, kt1);
        bar();
        __builtin_amdgcn_s_setprio(1);
        #pragma unroll
        for (int m = 4; m < 8; m++)
            #pragma unroll
            for (int n = 0; n < 4; n++)
                acc[m][n] = __builtin_amdgcn_mfma_f32_16x16x32_bf16(a0[m - 4], b0[n], acc[m][n], 0, 0, 0);
        __builtin_amdgcn_s_setprio(0);
        bar();

        // ---- P3: reads ks1.hi A (4); deep stage B(t+2)h0; vmcnt(2); mfma ks1 m4-7
        #pragma unroll
        for (int m = 0; m < 4; m++) a1[m] = *(const s16x8*)(Ab + aOff[m + 4] + x1);
        if (s2) STAGE_B(b, 0, kt2);
        if (s2) asm volatile("s_waitcnt vmcnt(2)" ::: "memory");
        else    asm volatile("s_waitcnt vmcnt(0)" ::: "memory");
        bar();
        __builtin_amdgcn_s_setprio(1);
        #pragma unroll
        for (int m = 4; m < 8; m++)
            #pragma unroll
            for (int n = 0; n < 4; n++)
                acc[m][n] = __builtin_amdgcn_mfma_f32_16x16x32_bf16(a1[m - 4], b1[n], acc[m][n], 0, 0, 0);
        __builtin_amdgcn_s_setprio(0);
        bar();
    }
#undef STAGE_A
#undef STAGE_B

    // epilogue: row = (lane>>4)*4 + r, col = lane&15 per 16x16 frag
    #pragma unroll
    for (int m = 0; m < 8; m++) {
        int rbase = j0 + wm * 128 + m * 16 + kg * 4;
        float dv[4];
        #pragma unroll
        for (int r = 0; r < 4; r++) dv[r] = dinv[rbase + r];
        #pragma unroll
        for (int n = 0; n < 4; n++) {
            int gcol = c0 + wn * 64 + n * 16 + fr;
            float bb = bias[gcol & (DH - 1)];
            #pragma unroll
            for (int r = 0; r < 4; r++) {
                float v = acc[m][n][r] * dv[r] + bb;
                v = v > 0.f ? v : 0.f;
                H[(size_t)(rbase + r) * NN + gcol] = f2bf(v);
            }
        }
    }
}

// ---------- gemm2 (128x128) with FUSED softmax epilogue -> writes out directly ----------
// logit[j][b*32+g] = dinv_j * sum_i M[j][i]*ZT[b*32+g][i] + g2b[g]; out = softmax_g
__global__ __launch_bounds__(256) void gemm_sm(
    const unsigned short* __restrict__ A, const unsigned short* __restrict__ Bt,
    float* __restrict__ out, const float* __restrict__ dinv,
    const float* __restrict__ bias, int K)
{
    constexpr int BK = 64;
    __shared__ __align__(16) unsigned short Asm[128 * BK];
    __shared__ __align__(16) unsigned short Bsm[128 * BK];
    const int tid = threadIdx.x;
    const int lane = tid & 63;
    const int w = tid >> 6;
    const int wm = w >> 1, wn = w & 1;
    const int c0 = blockIdx.x * 128;
    const int j0 = blockIdx.y * 128;

    int srcOff[4];
    #pragma unroll
    for (int q = 0; q < 4; q++) {
        int cid = w * 256 + q * 64 + lane;
        int row = cid >> 3, kc = cid & 7;
        srcOff[q] = row * K + ((kc ^ (row & 7)) << 3);
    }
    const int fr = lane & 15;
    const int kg = lane >> 4;

    f32x4 acc[4][4] = {};
    const unsigned short* Abase = A + (size_t)j0 * K;
    const unsigned short* Bbase = Bt + (size_t)c0 * K;

    for (int kt = 0; kt < K; kt += BK) {
        __syncthreads();
        const unsigned short* Ag = Abase + kt;
        const unsigned short* Bg = Bbase + kt;
        #pragma unroll
        for (int q = 0; q < 4; q++)
            gload16(Ag + srcOff[q], &Asm[(w * 256 + q * 64) * 8]);
        #pragma unroll
        for (int q = 0; q < 4; q++)
            gload16(Bg + srcOff[q], &Bsm[(w * 256 + q * 64) * 8]);
        __syncthreads();

        s16x8 af[2][4], bf[2][4];
        #pragma unroll
        for (int ks = 0; ks < 2; ks++) {
            int kc = ks * 4 + kg;
            #pragma unroll
            for (int m = 0; m < 4; m++) {
                int row = wm * 64 + m * 16 + fr;
                af[ks][m] = *(const s16x8*)((const char*)Asm + row * 128 + ((kc ^ (row & 7)) << 4));
            }
            #pragma unroll
            for (int n = 0; n < 4; n++) {
                int row = wn * 64 + n * 16 + fr;
                bf[ks][n] = *(const s16x8*)((const char*)Bsm + row * 128 + ((kc ^ (row & 7)) << 4));
            }
        }
        #pragma unroll
        for (int ks = 0; ks < 2; ks++)
            #pragma unroll
            for (int m = 0; m < 4; m++)
                #pragma unroll
                for (int n = 0; n < 4; n++)
                    acc[m][n] = __builtin_amdgcn_mfma_f32_16x16x32_bf16(
                        af[ks][m], bf[ks][n], acc[m][n], 0, 0, 0);
    }

    // fused epilogue: cols c = c0 + wn*64 + n*16 + fr; g = c&31 = fr (n even) / fr+16 (n odd)
    // b-group = c>>5 = (c0>>5) + wn*2 + (n>>1). 16-lane group (same kg) holds all g.
    const float b_lo = bias[fr], b_hi = bias[fr + 16];
    #pragma unroll
    for (int m = 0; m < 4; m++) {
        int rbase = j0 + wm * 64 + m * 16 + kg * 4;
        float dv[4];
        #pragma unroll
        for (int r = 0; r < 4; r++) dv[r] = dinv[rbase + r];
        #pragma unroll
        for (int np = 0; np < 2; np++) {
            int bg = (c0 >> 5) + wn * 2 + np;       // batch index 0..31
            #pragma unroll
            for (int r = 0; r < 4; r++) {
                int row = rbase + r;                 // node j
                float v0 = acc[m][np * 2][r]     * dv[r] + b_lo;   // g = fr
                float v1 = acc[m][np * 2 + 1][r] * dv[r] + b_hi;   // g = fr+16
                float mx = fmaxf(v0, v1);
                #pragma unroll
                for (int d = 8; d; d >>= 1) mx = fmaxf(mx, __shfl_xor(mx, d));
                float e0 = expf(v0 - mx), e1 = expf(v1 - mx);
                float s = e0 + e1;
                #pragma unroll
                for (int d = 8; d; d >>= 1) s += __shfl_xor(s, d);
                float inv = 1.0f / s;
                size_t ob = ((size_t)bg * NN + row) * DOUT;
                out[ob + fr]      = e0 * inv;
                out[ob + fr + 16] = e1 * inv;
            }
        }
    }
}

// ---------------- ZT[c2=b*32+g][j] = bf16( dinv_j * (h[b,j,:] @ W2[:,g]) ) ----------------
__global__ __launch_bounds__(256) void k_z(
    const unsigned short* __restrict__ H, const float* __restrict__ W2,
    const float* __restrict__ dinv, unsigned short* __restrict__ ZT)
{
    __shared__ __align__(16) unsigned short Hs[128][136];
    __shared__ __align__(16) float w2s[DH][DOUT];
    int j0 = blockIdx.x * 128, b = blockIdx.y;
    int tid = threadIdx.x;
    #pragma unroll
    for (int q = 0; q < 8; q++) {
        int idx = q * 256 + tid;
        int row = idx >> 4, c = idx & 15;
        *(s16x8*)&Hs[row][c * 8] =
            *(const s16x8*)(H + (size_t)(j0 + row) * (NB * DH) + b * DH + c * 8);
    }
    #pragma unroll
    for (int q = 0; q < 4; q++) {
        int idx = q * 256 + tid;
        int row = idx >> 3, c4 = idx & 7;
        *(f32x4*)&w2s[row][c4 * 4] = ((const f32x4*)W2)[idx];
    }
    __syncthreads();
    int g = tid & 31, jq = tid >> 5;
    #pragma unroll
    for (int t = 0; t < 2; t++) {
        int jb = (t * 8 + jq) * 8;
        float accz[8] = {};
        for (int f8 = 0; f8 < 16; f8++) {
            float wv[8];
            #pragma unroll
            for (int e = 0; e < 8; e++) wv[e] = w2s[f8 * 8 + e][g];
            #pragma unroll
            for (int jj = 0; jj < 8; jj++) {
                s16x8 hc = *(const s16x8*)&Hs[jb + jj][f8 * 8];
                #pragma unroll
                for (int e = 0; e < 8; e++)
                    accz[jj] += bf2f((unsigned short)hc[e]) * wv[e];
            }
        }
        s16x8 pk;
        #pragma unroll
        for (int jj = 0; jj < 8; jj++)
            pk[jj] = (short)f2bf(accz[jj] * dinv[j0 + jb + jj]);
        *(s16x8*)(ZT + (size_t)(b * DOUT + g) * NN + j0 + jb) = pk;
    }
}

extern "C" void kernel_launch(void* const* d_in, const int* in_sizes, int n_in,
                              void* d_out, int out_size, void* d_ws, size_t ws_size,
                              hipStream_t stream)
{
    (void)in_sizes; (void)n_in; (void)out_size; (void)ws_size;
    const float* x    = (const float*)d_in[0];
    const float* emb1 = (const float*)d_in[1];
    const float* emb2 = (const float*)d_in[2];
    const float* l1w  = (const float*)d_in[3];
    const float* l1b  = (const float*)d_in[4];
    const float* l2w  = (const float*)d_in[5];
    const float* l2b  = (const float*)d_in[6];
    const float* g1w  = (const float*)d_in[7];
    const float* g1b  = (const float*)d_in[8];
    const float* g2w  = (const float*)d_in[9];
    const float* g2b  = (const float*)d_in[10];
    float* out = (float*)d_out;

    char* w = (char*)d_ws;
    float* n1 = (float*)w;                    w += NN * DIM * 4;
    float* n2 = (float*)w;                    w += NN * DIM * 4;
    int* deg = (int*)w;                       w += NN * 4;
    float* dinv = (float*)w;                  w += NN * 4;
    unsigned int* mtb = (unsigned int*)w;     w += (size_t)NN * 128 * 4;
    unsigned short* MT = (unsigned short*)w;  w += (size_t)NN * NN * 2;
    unsigned short* YT = (unsigned short*)w;  w += (size_t)NN * NN * 2;
    unsigned short* H  = (unsigned short*)w;  w += (size_t)NN * NN * 2;
    unsigned short* ZT = (unsigned short*)w;  w += (size_t)(NB * DOUT) * NN * 2;

    hipMemsetAsync(deg, 0, NN * sizeof(int), stream);
    k_embed<<<1280, 256, 0, stream>>>(emb1, emb2, l1w, l1b, l2w, l2b, n1, n2);
    k_adj2<<<dim3(64, 64), 256, 0, stream>>>(n1, n2, mtb, deg);
    k_dinv<<<16, 256, 0, stream>>>(deg, dinv);
    k_expand<<<2048, 256, 0, stream>>>(mtb, MT);
    k_y1<<<dim3(32, 32), 256, 0, stream>>>(x, g1w, dinv, YT);
    gemm8<<<256, 512, 0, stream>>>(MT, YT, H, dinv, g1b);
    k_z<<<dim3(32, 32), 256, 0, stream>>>(H, g2w, dinv, ZT);
    gemm_sm<<<dim3(8, 32), 256, 0, stream>>>(MT, ZT, out, dinv, g2b, NN);
}

// Round 5
// 403.993 us; speedup vs baseline: 1.0836x; 1.0836x over previous
//
#include <hip/hip_runtime.h>

typedef float f32x4 __attribute__((ext_vector_type(4)));
typedef short s16x8 __attribute__((ext_vector_type(8)));

#define NN 4096
#define NB 32
#define DIN 64
#define DH 128
#define DOUT 32
#define DIM 40

__device__ __forceinline__ unsigned short f2bf(float f) {
    unsigned int u = __float_as_uint(f);
    unsigned int r = (u + 0x7FFFu + ((u >> 16) & 1u)) >> 16;
    return (unsigned short)r;
}
__device__ __forceinline__ float bf2f(unsigned short h) {
    return __uint_as_float(((unsigned int)h) << 16);
}
__device__ __forceinline__ void gload16(const void* g, void* l) {
    __builtin_amdgcn_global_load_lds(
        (const __attribute__((address_space(1))) unsigned int*)g,
        (__attribute__((address_space(3))) unsigned int*)l, 16, 0, 0);
}
__device__ __forceinline__ void bar() {
    asm volatile("" ::: "memory");
    __builtin_amdgcn_s_barrier();
    asm volatile("" ::: "memory");
}

// ---------------- stage 1: n1/n2 = tanh(3*(emb @ W + b)) ----------------
__global__ __launch_bounds__(256) void k_embed(
    const float* __restrict__ emb1, const float* __restrict__ emb2,
    const float* __restrict__ l1w, const float* __restrict__ l1b,
    const float* __restrict__ l2w, const float* __restrict__ l2b,
    float* __restrict__ n1, float* __restrict__ n2)
{
    __shared__ float w1s[DIM * DIM], w2s[DIM * DIM], b1s[DIM], b2s[DIM];
    int tid = threadIdx.x;
    for (int i = tid; i < DIM * DIM; i += 256) { w1s[i] = l1w[i]; w2s[i] = l2w[i]; }
    if (tid < DIM) { b1s[tid] = l1b[tid]; b2s[tid] = l2b[tid]; }
    __syncthreads();
    int t = blockIdx.x * 256 + tid;          // < 2*4096*40 = 327680
    int half = t >= NN * DIM;
    int r = t - half * (NN * DIM);
    int i = r / DIM, c = r - i * DIM;
    const float* emb = half ? emb2 : emb1;
    const float* ws  = half ? w2s : w1s;
    float acc = half ? b2s[c] : b1s[c];
    for (int k = 0; k < DIM; k++) acc += emb[i * DIM + k] * ws[k * DIM + c];
    (half ? n2 : n1)[r] = tanhf(3.0f * acc);
}

// ---------------- stage 2: adjacency bits + degree (register-tiled) ----------------
#define APAD 44
#define TPAD 69
__global__ __launch_bounds__(256) void k_adj2(
    const float* __restrict__ n1, const float* __restrict__ n2,
    unsigned int* __restrict__ mtb, int* __restrict__ deg)
{
    const int bi = blockIdx.x, bj = blockIdx.y;
    if (bj < bi) return;
    const bool diag = (bi == bj);
    const int i0 = bi * 64, j0 = bj * 64;

    __shared__ __align__(16) float n1i[64 * APAD], n1j[64 * APAD];
    __shared__ __align__(16) float n2iT[DIM * 64], n2jT[DIM * 64];
    __shared__ float T1[64 * TPAD], T2[64 * TPAD];

    const int tid = threadIdx.x;
    for (int idx = tid; idx < 64 * DIM; idx += 256) {
        int r = idx / DIM, c = idx - r * DIM;
        n1i[r * APAD + c] = n1[(i0 + r) * DIM + c];
        n1j[r * APAD + c] = n1[(j0 + r) * DIM + c];
    }
    for (int idx = tid; idx < DIM * 64; idx += 256) {
        int k = idx >> 6, col = idx & 63;
        n2iT[k * 64 + col] = n2[(i0 + col) * DIM + k];
        n2jT[k * 64 + col] = n2[(j0 + col) * DIM + k];
    }
    __syncthreads();

    const int tq = tid & 15, tp = tid >> 4;
    const int rowb = tp * 4, colb = tq * 4;
    f32x4 acc1[4] = {}, acc2[4] = {};
    for (int k4 = 0; k4 < DIM; k4 += 4) {
        f32x4 a1[4], a2[4];
        #pragma unroll
        for (int di = 0; di < 4; di++) {
            a1[di] = *(const f32x4*)&n1i[(rowb + di) * APAD + k4];
            a2[di] = *(const f32x4*)&n1j[(rowb + di) * APAD + k4];
        }
        #pragma unroll
        for (int kk = 0; kk < 4; kk++) {
            f32x4 b2 = *(const f32x4*)&n2jT[(k4 + kk) * 64 + colb];
            f32x4 b1 = *(const f32x4*)&n2iT[(k4 + kk) * 64 + colb];
            #pragma unroll
            for (int di = 0; di < 4; di++) {
                acc1[di] += a1[di][kk] * b2;   // T1[p][q] = n1[I]·n2[J]
                acc2[di] += a2[di][kk] * b1;   // T2[p][q] = n1[J]·n2[I]
            }
        }
    }
    #pragma unroll
    for (int di = 0; di < 4; di++)
        #pragma unroll
        for (int dq = 0; dq < 4; dq++) {
            T1[(rowb + di) * TPAD + colb + dq] = acc1[di][dq];
            T2[(rowb + di) * TPAD + colb + dq] = acc2[di][dq];
        }
    __syncthreads();

    const int lane = tid & 63, w = tid >> 6;
    const int p = lane;
    #pragma unroll
    for (int qq = 0; qq < 16; qq++) {
        int q = w * 16 + qq;
        float t1  = T1[p * TPAD + q];
        float t2b = T2[q * TPAD + p];
        bool bit = (t1 > t2b) || (diag && p == q);
        unsigned long long mask = __ballot(bit);
        if (lane == 0) {
            mtb[(size_t)(j0 + q) * 128 + (i0 >> 5)]     = (unsigned int)mask;
            mtb[(size_t)(j0 + q) * 128 + (i0 >> 5) + 1] = (unsigned int)(mask >> 32);
            atomicAdd(&deg[j0 + q], (int)__popcll(mask));
        }
        if (!diag) {
            float t2  = T2[p * TPAD + q];
            float t1b = T1[q * TPAD + p];
            unsigned long long m2 = __ballot(t2 > t1b);
            if (lane == 0) {
                mtb[(size_t)(i0 + q) * 128 + (j0 >> 5)]     = (unsigned int)m2;
                mtb[(size_t)(i0 + q) * 128 + (j0 >> 5) + 1] = (unsigned int)(m2 >> 32);
                atomicAdd(&deg[i0 + q], (int)__popcll(m2));
            }
        }
    }
}

__global__ void k_dinv(const int* __restrict__ deg, float* __restrict__ dinv) {
    int i = blockIdx.x * 256 + threadIdx.x;
    if (i < NN) dinv[i] = 1.0f / sqrtf((float)deg[i]);
}

// bits -> bf16 0/1 matrix MT[j][i]
__global__ __launch_bounds__(256) void k_expand(
    const unsigned int* __restrict__ mtb, unsigned short* __restrict__ MT)
{
    int idx = blockIdx.x * 256 + threadIdx.x;   // < 4096*128
    unsigned int bits = mtb[idx];
    size_t base = (size_t)idx * 32;
    #pragma unroll
    for (int q = 0; q < 4; q++) {
        s16x8 v;
        #pragma unroll
        for (int e = 0; e < 8; e++)
            v[e] = (short)(((bits >> (q * 8 + e)) & 1u) ? 0x3F80 : 0);
        *(s16x8*)(MT + base + q * 8) = v;
    }
}

// ---------------- YT[c=b*128+f][i] = bf16( dinv_i * (x[b,i,:] @ W1[:,f]) ) ----------------
__global__ __launch_bounds__(256) void k_y1(
    const float* __restrict__ x, const float* __restrict__ W1,
    const float* __restrict__ dinv, unsigned short* __restrict__ YT)
{
    __shared__ __align__(16) float xs[128][DIN];
    __shared__ __align__(16) float w1s[DIN][DH];
    int i0 = blockIdx.x * 128, b = blockIdx.y;
    int tid = threadIdx.x;
    const f32x4* xg = (const f32x4*)(x + ((size_t)(b * NN + i0)) * DIN);
    #pragma unroll
    for (int q = 0; q < 8; q++) {
        int idx = q * 256 + tid;
        int row = idx >> 4, c4 = idx & 15;
        *(f32x4*)&xs[row][c4 * 4] = xg[(size_t)row * 16 + c4];
    }
    #pragma unroll
    for (int q = 0; q < 8; q++) {
        int idx = q * 256 + tid;
        int row = idx >> 5, c4 = idx & 31;
        *(f32x4*)&w1s[row][c4 * 4] = ((const f32x4*)W1)[idx];
    }
    __syncthreads();
    int tf = tid & 15, ti = tid >> 4;
    f32x4 t0[8] = {}, t1[8] = {};
    for (int k4 = 0; k4 < DIN; k4 += 4) {
        f32x4 xv[8];
        #pragma unroll
        for (int ii = 0; ii < 8; ii++) xv[ii] = *(const f32x4*)&xs[ti * 8 + ii][k4];
        #pragma unroll
        for (int kk = 0; kk < 4; kk++) {
            f32x4 w0 = *(const f32x4*)&w1s[k4 + kk][tf * 8];
            f32x4 w1v = *(const f32x4*)&w1s[k4 + kk][tf * 8 + 4];
            #pragma unroll
            for (int ii = 0; ii < 8; ii++) {
                float s = xv[ii][kk];
                t0[ii] += s * w0;
                t1[ii] += s * w1v;
            }
        }
    }
    float dvv[8];
    #pragma unroll
    for (int ii = 0; ii < 8; ii++) dvv[ii] = dinv[i0 + ti * 8 + ii];
    #pragma unroll
    for (int ff = 0; ff < 8; ff++) {
        s16x8 pk;
        #pragma unroll
        for (int ii = 0; ii < 8; ii++) {
            float v = (ff < 4 ? t0[ii][ff] : t1[ii][ff - 4]) * dvv[ii];
            pk[ii] = (short)f2bf(v);
        }
        *(s16x8*)(YT + ((size_t)(b * DH + tf * 8 + ff)) * NN + i0 + ti * 8) = pk;
    }
}

// ======== gemm1: 256x256, BK=64, 8 waves; R2 deep staging + balanced 8/8/8/0 reads ========
// Stages during tile t: P0 -> B(t+1)h1 [buf^1]; P3 -> A(t+2)h0, A(t+2)h1, B(t+2)h0 [buf].
// vmcnt(6) at P3: 14 in flight, drain 8 oldest == exactly tile t+1 complete.
// All As[b]/Bs[b] reads complete by end of P2 -> P3's same-buffer stages are race-free.
__global__ __launch_bounds__(512, 2) void gemm8(
    const unsigned short* __restrict__ A, const unsigned short* __restrict__ Bt,
    unsigned short* __restrict__ H, const float* __restrict__ dinv,
    const float* __restrict__ bias)
{
    constexpr int K = NN;          // 4096
    constexpr int NT = K / 64;     // 64 K-tiles
    __shared__ __align__(16) unsigned short As[2][256 * 64];   // 64 KB
    __shared__ __align__(16) unsigned short Bs[2][256 * 64];   // 64 KB

    const int tid = threadIdx.x;
    const int lane = tid & 63;
    const int w = tid >> 6;                 // wave 0..7
    const int wm = w >> 2, wn = w & 3;      // 2 x 4 wave grid
    const int fr = lane & 15, kg = lane >> 4;

    const int bid = blockIdx.x;             // 256 blocks -> XCD swizzle
    const int swz = (bid & 7) * 32 + (bid >> 3);
    const int bx = swz & 15, by = swz >> 4;
    const int c0 = bx * 256, j0 = by * 256;

    const int cid0 = w * 128 + lane, cid1 = cid0 + 64;
    const int r0 = cid0 >> 3, k0c = cid0 & 7;
    const int r1 = cid1 >> 3, k1c = cid1 & 7;
    const int so0 = r0 * K + ((k0c ^ (r0 & 7)) << 3);   // ushort units
    const int so1 = r1 * K + ((k1c ^ (r1 & 7)) << 3);
    const int lb0 = (w * 2 + 0) * 512;                  // ushort units
    const int lb1 = (w * 2 + 1) * 512;

    const unsigned short* Aj = A + (size_t)j0 * K;
    const unsigned short* Bc = Bt + (size_t)c0 * K;

#define STAGE_A(buf, half, kt) do { \
    const unsigned short* g_ = Aj + (size_t)((half) * 128) * K + (kt); \
    gload16(g_ + so0, &As[buf][(half) * 8192 + lb0]); \
    gload16(g_ + so1, &As[buf][(half) * 8192 + lb1]); } while (0)
#define STAGE_B(buf, half, kt) do { \
    const unsigned short* g_ = Bc + (size_t)((half) * 128) * K + (kt); \
    gload16(g_ + so0, &Bs[buf][(half) * 8192 + lb0]); \
    gload16(g_ + so1, &Bs[buf][(half) * 8192 + lb1]); } while (0)

    // prologue: tile0 complete (8) + tile1 {Ah0, Ah1, Bh0} (6)
    STAGE_A(0, 0, 0);  STAGE_A(0, 1, 0);
    STAGE_B(0, 0, 0);  STAGE_B(0, 1, 0);
    STAGE_A(1, 0, 64); STAGE_A(1, 1, 64);
    STAGE_B(1, 0, 64);
    asm volatile("s_waitcnt vmcnt(6)" ::: "memory");   // tile0's 8 landed
    bar();

    const int x0 = ((kg) ^ (fr & 7)) << 4;        // ks0 chunk, bytes
    const int x1 = ((4 + kg) ^ (fr & 7)) << 4;    // ks1 chunk, bytes
    int aOff[8], bOff[4];
    #pragma unroll
    for (int m = 0; m < 8; m++) aOff[m] = (wm * 128 + m * 16 + fr) * 128;
    #pragma unroll
    for (int n = 0; n < 4; n++) bOff[n] = (wn * 64 + n * 16 + fr) * 128;

    f32x4 acc[8][4] = {};

    for (int t = 0; t < NT; t++) {
        const int b = t & 1;
        const char* Ab = (const char*)As[b];
        const char* Bb = (const char*)Bs[b];
        const int kt1 = (t + 1) * 64, kt2 = (t + 2) * 64;
        const bool s1 = (t + 1) < NT, s2 = (t + 2) < NT;
        s16x8 af0[8], af1[8], bf0[4], bf1[4];

        // ---- P0: read af0.lo + bf0 (8); stage B(t+1)h1; mfma ks0 m0-3
        #pragma unroll
        for (int m = 0; m < 4; m++) af0[m] = *(const s16x8*)(Ab + aOff[m] + x0);
        #pragma unroll
        for (int n = 0; n < 4; n++) bf0[n] = *(const s16x8*)(Bb + bOff[n] + x0);
        if (s1) STAGE_B(b ^ 1, 1, kt1);
        bar();
        __builtin_amdgcn_s_setprio(1);
        #pragma unroll
        for (int m = 0; m < 4; m++)
            #pragma unroll
            for (int n = 0; n < 4; n++)
                acc[m][n] = __builtin_amdgcn_mfma_f32_16x16x32_bf16(af0[m], bf0[n], acc[m][n], 0, 0, 0);
        __builtin_amdgcn_s_setprio(0);
        bar();

        // ---- P1: read af0.hi + af1.lo (8); mfma ks0 m4-7
        #pragma unroll
        for (int m = 4; m < 8; m++) af0[m] = *(const s16x8*)(Ab + aOff[m] + x0);
        #pragma unroll
        for (int m = 0; m < 4; m++) af1[m] = *(const s16x8*)(Ab + aOff[m] + x1);
        bar();
        __builtin_amdgcn_s_setprio(1);
        #pragma unroll
        for (int m = 4; m < 8; m++)
            #pragma unroll
            for (int n = 0; n < 4; n++)
                acc[m][n] = __builtin_amdgcn_mfma_f32_16x16x32_bf16(af0[m], bf0[n], acc[m][n], 0, 0, 0);
        __builtin_amdgcn_s_setprio(0);
        bar();

        // ---- P2: read af1.hi + bf1 (8); mfma ks1 m0-3
        #pragma unroll
        for (int m = 4; m < 8; m++) af1[m] = *(const s16x8*)(Ab + aOff[m] + x1);
        #pragma unroll
        for (int n = 0; n < 4; n++) bf1[n] = *(const s16x8*)(Bb + bOff[n] + x1);
        bar();
        __builtin_amdgcn_s_setprio(1);
        #pragma unroll
        for (int m = 0; m < 4; m++)
            #pragma unroll
            for (int n = 0; n < 4; n++)
                acc[m][n] = __builtin_amdgcn_mfma_f32_16x16x32_bf16(af1[m], bf1[n], acc[m][n], 0, 0, 0);
        __builtin_amdgcn_s_setprio(0);
        bar();

        // ---- P3: stage A(t+2)h0, A(t+2)h1, B(t+2)h0; vmcnt(6); mfma ks1 m4-7
        if (s2) {
            STAGE_A(b, 0, kt2);
            STAGE_A(b, 1, kt2);
            STAGE_B(b, 0, kt2);
            asm volatile("s_waitcnt vmcnt(6)" ::: "memory");
        } else {
            asm volatile("s_waitcnt vmcnt(0)" ::: "memory");
        }
        bar();
        __builtin_amdgcn_s_setprio(1);
        #pragma unroll
        for (int m = 4; m < 8; m++)
            #pragma unroll
            for (int n = 0; n < 4; n++)
                acc[m][n] = __builtin_amdgcn_mfma_f32_16x16x32_bf16(af1[m], bf1[n], acc[m][n], 0, 0, 0);
        __builtin_amdgcn_s_setprio(0);
        bar();
    }
#undef STAGE_A
#undef STAGE_B

    // epilogue: row = (lane>>4)*4 + r, col = lane&15 per 16x16 frag
    #pragma unroll
    for (int m = 0; m < 8; m++) {
        int rbase = j0 + wm * 128 + m * 16 + kg * 4;
        float dv[4];
        #pragma unroll
        for (int r = 0; r < 4; r++) dv[r] = dinv[rbase + r];
        #pragma unroll
        for (int n = 0; n < 4; n++) {
            int gcol = c0 + wn * 64 + n * 16 + fr;
            float bb = bias[gcol & (DH - 1)];
            #pragma unroll
            for (int r = 0; r < 4; r++) {
                float v = acc[m][n][r] * dv[r] + bb;
                v = v > 0.f ? v : 0.f;
                H[(size_t)(rbase + r) * NN + gcol] = f2bf(v);
            }
        }
    }
}

// ---------- gemm2 (128x128) with FUSED softmax epilogue -> writes out directly ----------
__global__ __launch_bounds__(256) void gemm_sm(
    const unsigned short* __restrict__ A, const unsigned short* __restrict__ Bt,
    float* __restrict__ out, const float* __restrict__ dinv,
    const float* __restrict__ bias, int K)
{
    constexpr int BK = 64;
    __shared__ __align__(16) unsigned short Asm[128 * BK];
    __shared__ __align__(16) unsigned short Bsm[128 * BK];
    const int tid = threadIdx.x;
    const int lane = tid & 63;
    const int w = tid >> 6;
    const int wm = w >> 1, wn = w & 1;
    const int c0 = blockIdx.x * 128;
    const int j0 = blockIdx.y * 128;

    int srcOff[4];
    #pragma unroll
    for (int q = 0; q < 4; q++) {
        int cid = w * 256 + q * 64 + lane;
        int row = cid >> 3, kc = cid & 7;
        srcOff[q] = row * K + ((kc ^ (row & 7)) << 3);
    }
    const int fr = lane & 15;
    const int kg = lane >> 4;

    f32x4 acc[4][4] = {};
    const unsigned short* Abase = A + (size_t)j0 * K;
    const unsigned short* Bbase = Bt + (size_t)c0 * K;

    for (int kt = 0; kt < K; kt += BK) {
        __syncthreads();
        const unsigned short* Ag = Abase + kt;
        const unsigned short* Bg = Bbase + kt;
        #pragma unroll
        for (int q = 0; q < 4; q++)
            gload16(Ag + srcOff[q], &Asm[(w * 256 + q * 64) * 8]);
        #pragma unroll
        for (int q = 0; q < 4; q++)
            gload16(Bg + srcOff[q], &Bsm[(w * 256 + q * 64) * 8]);
        __syncthreads();

        s16x8 af[2][4], bf[2][4];
        #pragma unroll
        for (int ks = 0; ks < 2; ks++) {
            int kc = ks * 4 + kg;
            #pragma unroll
            for (int m = 0; m < 4; m++) {
                int row = wm * 64 + m * 16 + fr;
                af[ks][m] = *(const s16x8*)((const char*)Asm + row * 128 + ((kc ^ (row & 7)) << 4));
            }
            #pragma unroll
            for (int n = 0; n < 4; n++) {
                int row = wn * 64 + n * 16 + fr;
                bf[ks][n] = *(const s16x8*)((const char*)Bsm + row * 128 + ((kc ^ (row & 7)) << 4));
            }
        }
        #pragma unroll
        for (int ks = 0; ks < 2; ks++)
            #pragma unroll
            for (int m = 0; m < 4; m++)
                #pragma unroll
                for (int n = 0; n < 4; n++)
                    acc[m][n] = __builtin_amdgcn_mfma_f32_16x16x32_bf16(
                        af[ks][m], bf[ks][n], acc[m][n], 0, 0, 0);
    }

    // fused epilogue: g = fr (n even) / fr+16 (n odd); batch = (c0>>5) + wn*2 + (n>>1)
    const float b_lo = bias[fr], b_hi = bias[fr + 16];
    #pragma unroll
    for (int m = 0; m < 4; m++) {
        int rbase = j0 + wm * 64 + m * 16 + kg * 4;
        float dv[4];
        #pragma unroll
        for (int r = 0; r < 4; r++) dv[r] = dinv[rbase + r];
        #pragma unroll
        for (int np = 0; np < 2; np++) {
            int bg = (c0 >> 5) + wn * 2 + np;       // batch index 0..31
            #pragma unroll
            for (int r = 0; r < 4; r++) {
                int row = rbase + r;                 // node j
                float v0 = acc[m][np * 2][r]     * dv[r] + b_lo;   // g = fr
                float v1 = acc[m][np * 2 + 1][r] * dv[r] + b_hi;   // g = fr+16
                float mx = fmaxf(v0, v1);
                #pragma unroll
                for (int d = 8; d; d >>= 1) mx = fmaxf(mx, __shfl_xor(mx, d));
                float e0 = expf(v0 - mx), e1 = expf(v1 - mx);
                float s = e0 + e1;
                #pragma unroll
                for (int d = 8; d; d >>= 1) s += __shfl_xor(s, d);
                float inv = 1.0f / s;
                size_t ob = ((size_t)bg * NN + row) * DOUT;
                out[ob + fr]      = e0 * inv;
                out[ob + fr + 16] = e1 * inv;
            }
        }
    }
}

// ---------------- ZT[c2=b*32+g][j] = bf16( dinv_j * (h[b,j,:] @ W2[:,g]) ) ----------------
__global__ __launch_bounds__(256) void k_z(
    const unsigned short* __restrict__ H, const float* __restrict__ W2,
    const float* __restrict__ dinv, unsigned short* __restrict__ ZT)
{
    __shared__ __align__(16) unsigned short Hs[128][136];
    __shared__ __align__(16) float w2s[DH][DOUT];
    int j0 = blockIdx.x * 128, b = blockIdx.y;
    int tid = threadIdx.x;
    #pragma unroll
    for (int q = 0; q < 8; q++) {
        int idx = q * 256 + tid;
        int row = idx >> 4, c = idx & 15;
        *(s16x8*)&Hs[row][c * 8] =
            *(const s16x8*)(H + (size_t)(j0 + row) * (NB * DH) + b * DH + c * 8);
    }
    #pragma unroll
    for (int q = 0; q < 4; q++) {
        int idx = q * 256 + tid;
        int row = idx >> 3, c4 = idx & 7;
        *(f32x4*)&w2s[row][c4 * 4] = ((const f32x4*)W2)[idx];
    }
    __syncthreads();
    int g = tid & 31, jq = tid >> 5;
    #pragma unroll
    for (int t = 0; t < 2; t++) {
        int jb = (t * 8 + jq) * 8;
        float accz[8] = {};
        for (int f8 = 0; f8 < 16; f8++) {
            float wv[8];
            #pragma unroll
            for (int e = 0; e < 8; e++) wv[e] = w2s[f8 * 8 + e][g];
            #pragma unroll
            for (int jj = 0; jj < 8; jj++) {
                s16x8 hc = *(const s16x8*)&Hs[jb + jj][f8 * 8];
                #pragma unroll
                for (int e = 0; e < 8; e++)
                    accz[jj] += bf2f((unsigned short)hc[e]) * wv[e];
            }
        }
        s16x8 pk;
        #pragma unroll
        for (int jj = 0; jj < 8; jj++)
            pk[jj] = (short)f2bf(accz[jj] * dinv[j0 + jb + jj]);
        *(s16x8*)(ZT + (size_t)(b * DOUT + g) * NN + j0 + jb) = pk;
    }
}

extern "C" void kernel_launch(void* const* d_in, const int* in_sizes, int n_in,
                              void* d_out, int out_size, void* d_ws, size_t ws_size,
                              hipStream_t stream)
{
    (void)in_sizes; (void)n_in; (void)out_size; (void)ws_size;
    const float* x    = (const float*)d_in[0];
    const float* emb1 = (const float*)d_in[1];
    const float* emb2 = (const float*)d_in[2];
    const float* l1w  = (const float*)d_in[3];
    const float* l1b  = (const float*)d_in[4];
    const float* l2w  = (const float*)d_in[5];
    const float* l2b  = (const float*)d_in[6];
    const float* g1w  = (const float*)d_in[7];
    const float* g1b  = (const float*)d_in[8];
    const float* g2w  = (const float*)d_in[9];
    const float* g2b  = (const float*)d_in[10];
    float* out = (float*)d_out;

    char* w = (char*)d_ws;
    float* n1 = (float*)w;                    w += NN * DIM * 4;
    float* n2 = (float*)w;                    w += NN * DIM * 4;
    int* deg = (int*)w;                       w += NN * 4;
    float* dinv = (float*)w;                  w += NN * 4;
    unsigned int* mtb = (unsigned int*)w;     w += (size_t)NN * 128 * 4;
    unsigned short* MT = (unsigned short*)w;  w += (size_t)NN * NN * 2;
    unsigned short* YT = (unsigned short*)w;  w += (size_t)NN * NN * 2;
    unsigned short* H  = (unsigned short*)w;  w += (size_t)NN * NN * 2;
    unsigned short* ZT = (unsigned short*)w;  w += (size_t)(NB * DOUT) * NN * 2;

    hipMemsetAsync(deg, 0, NN * sizeof(int), stream);
    k_embed<<<1280, 256, 0, stream>>>(emb1, emb2, l1w, l1b, l2w, l2b, n1, n2);
    k_adj2<<<dim3(64, 64), 256, 0, stream>>>(n1, n2, mtb, deg);
    k_dinv<<<16, 256, 0, stream>>>(deg, dinv);
    k_expand<<<2048, 256, 0, stream>>>(mtb, MT);
    k_y1<<<dim3(32, 32), 256, 0, stream>>>(x, g1w, dinv, YT);
    gemm8<<<256, 512, 0, stream>>>(MT, YT, H, dinv, g1b);
    k_z<<<dim3(32, 32), 256, 0, stream>>>(H, g2w, dinv, ZT);
    gemm_sm<<<dim3(8, 32), 256, 0, stream>>>(MT, ZT, out, dinv, g2b, NN);
}

// Round 6
// 324.848 us; speedup vs baseline: 1.3476x; 1.2436x over previous
//
#include <hip/hip_runtime.h>

typedef float f32x4 __attribute__((ext_vector_type(4)));
typedef short s16x8 __attribute__((ext_vector_type(8)));

#define NN 4096
#define NB 32
#define DIN 64
#define DH 128
#define DOUT 32
#define DIM 40
#define KADJ 768   // 9*80 split-blocks zero-padded to 768

__device__ __forceinline__ unsigned short f2bf(float f) {
    unsigned int u = __float_as_uint(f);
    unsigned int r = (u + 0x7FFFu + ((u >> 16) & 1u)) >> 16;
    return (unsigned short)r;
}
__device__ __forceinline__ float bf2f(unsigned short h) {
    return __uint_as_float(((unsigned int)h) << 16);
}
__device__ __forceinline__ void gload16(const void* g, void* l) {
    __builtin_amdgcn_global_load_lds(
        (const __attribute__((address_space(1))) unsigned int*)g,
        (__attribute__((address_space(3))) unsigned int*)l, 16, 0, 0);
}
__device__ __forceinline__ void bar() {
    asm volatile("" ::: "memory");
    __builtin_amdgcn_s_barrier();
    asm volatile("" ::: "memory");
}

// ---------------- stage 1: n1/n2 = tanh(3*(emb @ W + b)) ----------------
__global__ __launch_bounds__(256) void k_embed(
    const float* __restrict__ emb1, const float* __restrict__ emb2,
    const float* __restrict__ l1w, const float* __restrict__ l1b,
    const float* __restrict__ l2w, const float* __restrict__ l2b,
    float* __restrict__ n1, float* __restrict__ n2)
{
    __shared__ float w1s[DIM * DIM], w2s[DIM * DIM], b1s[DIM], b2s[DIM];
    int tid = threadIdx.x;
    for (int i = tid; i < DIM * DIM; i += 256) { w1s[i] = l1w[i]; w2s[i] = l2w[i]; }
    if (tid < DIM) { b1s[tid] = l1b[tid]; b2s[tid] = l2b[tid]; }
    __syncthreads();
    int t = blockIdx.x * 256 + tid;          // < 2*4096*40 = 327680
    int half = t >= NN * DIM;
    int r = t - half * (NN * DIM);
    int i = r / DIM, c = r - i * DIM;
    const float* emb = half ? emb2 : emb1;
    const float* ws  = half ? w2s : w1s;
    float acc = half ? b2s[c] : b1s[c];
    for (int k = 0; k < DIM; k++) acc += emb[i * DIM + k] * ws[k * DIM + c];
    (half ? n2 : n1)[r] = tanhf(3.0f * acc);
}

// ---------------- stage 2a: build split operands for the adjacency GEMM ----------------
// u[i] = (n1[i], -n2[i]) dim 80; v[j] = (n2[j], n1[j]) dim 80.
// 3-way bf16 split u = u0+u1+u2 (v likewise). K-block bq = 3p+q (p,q in 0..2):
//   Ux[i][80*bq+k] = u_p[i][k];  Vx[j][80*bq+k] = v_q[j][k]
// so  sum_K Vx[j]*Ux[i] = sum_{p,q} u_p[i]·v_q[j] ~= a[i][j] to ~2^-24 rel.
__global__ __launch_bounds__(256) void k_build_uv(
    const float* __restrict__ n1, const float* __restrict__ n2,
    unsigned short* __restrict__ Ux, unsigned short* __restrict__ Vx)
{
    __shared__ unsigned short Ul[16][KADJ], Vl[16][KADJ];
    const int tid = threadIdx.x;
    const int r = tid >> 4;                 // local node 0..15
    const int node = blockIdx.x * 16 + r;
    const int k0 = (tid & 15) * 5;          // 5 k's per thread (80 total)
    #pragma unroll
    for (int e = 0; e < 5; e++) {
        int k = k0 + e;
        float a = (k < DIM) ? n1[node * DIM + k] : -n2[node * DIM + k - DIM];
        float b = (k < DIM) ? n2[node * DIM + k] : n1[node * DIM + k - DIM];
        unsigned short u0 = f2bf(a); float ra = a - bf2f(u0);
        unsigned short u1 = f2bf(ra); ra -= bf2f(u1);
        unsigned short u2 = f2bf(ra);
        unsigned short v0 = f2bf(b); float rb = b - bf2f(v0);
        unsigned short v1 = f2bf(rb); rb -= bf2f(v1);
        unsigned short v2 = f2bf(rb);
        unsigned short uu[3] = {u0, u1, u2}, vv[3] = {v0, v1, v2};
        #pragma unroll
        for (int bq = 0; bq < 9; bq++) {
            Ul[r][80 * bq + k] = uu[bq / 3];
            Vl[r][80 * bq + k] = vv[bq % 3];
        }
    }
    {   // zero-pad 720..767
        int c = tid & 15;
        #pragma unroll
        for (int e = 0; e < 3; e++) { Ul[r][720 + c * 3 + e] = 0; Vl[r][720 + c * 3 + e] = 0; }
    }
    __syncthreads();
    for (int q = 0; q < 6; q++) {           // 16*768/8 = 1536 chunks
        int idx = q * 256 + tid;
        int rr = idx / 96, c8 = idx - rr * 96;
        size_t off = ((size_t)(blockIdx.x * 16 + rr)) * KADJ + c8 * 8;
        *(s16x8*)(Ux + off) = *(s16x8*)&Ul[rr][c8 * 8];
        *(s16x8*)(Vx + off) = *(s16x8*)&Vl[rr][c8 * 8];
    }
}

// ---------------- stage 2b: adjacency GEMM -> MT bits (bf16) + deg ----------------
// C[j][i] = Vx[j]·Ux[i] ~= a[i][j]; MT[j][i] = (C>0 || i==j) ? 1.0bf : 0;
// deg[j] += row-sum of bits.
__global__ __launch_bounds__(256) void gemm_adj(
    const unsigned short* __restrict__ V, const unsigned short* __restrict__ U,
    unsigned short* __restrict__ MT, int* __restrict__ deg)
{
    constexpr int K = KADJ;
    constexpr int BK = 64;
    __shared__ __align__(16) unsigned short Asm[128 * BK];
    __shared__ __align__(16) unsigned short Bsm[128 * BK];
    const int tid = threadIdx.x;
    const int lane = tid & 63;
    const int w = tid >> 6;
    const int wm = w >> 1, wn = w & 1;
    const int c0 = blockIdx.x * 128;   // i (cols)
    const int j0 = blockIdx.y * 128;   // j (rows)

    int srcOff[4];
    #pragma unroll
    for (int q = 0; q < 4; q++) {
        int cid = w * 256 + q * 64 + lane;
        int row = cid >> 3, kc = cid & 7;
        srcOff[q] = row * K + ((kc ^ (row & 7)) << 3);
    }
    const int fr = lane & 15;
    const int kg = lane >> 4;

    f32x4 acc[4][4] = {};
    const unsigned short* Abase = V + (size_t)j0 * K;
    const unsigned short* Bbase = U + (size_t)c0 * K;

    for (int kt = 0; kt < K; kt += BK) {
        __syncthreads();
        const unsigned short* Ag = Abase + kt;
        const unsigned short* Bg = Bbase + kt;
        #pragma unroll
        for (int q = 0; q < 4; q++)
            gload16(Ag + srcOff[q], &Asm[(w * 256 + q * 64) * 8]);
        #pragma unroll
        for (int q = 0; q < 4; q++)
            gload16(Bg + srcOff[q], &Bsm[(w * 256 + q * 64) * 8]);
        __syncthreads();

        s16x8 af[2][4], bf[2][4];
        #pragma unroll
        for (int ks = 0; ks < 2; ks++) {
            int kc = ks * 4 + kg;
            #pragma unroll
            for (int m = 0; m < 4; m++) {
                int row = wm * 64 + m * 16 + fr;
                af[ks][m] = *(const s16x8*)((const char*)Asm + row * 128 + ((kc ^ (row & 7)) << 4));
            }
            #pragma unroll
            for (int n = 0; n < 4; n++) {
                int row = wn * 64 + n * 16 + fr;
                bf[ks][n] = *(const s16x8*)((const char*)Bsm + row * 128 + ((kc ^ (row & 7)) << 4));
            }
        }
        #pragma unroll
        for (int ks = 0; ks < 2; ks++)
            #pragma unroll
            for (int m = 0; m < 4; m++)
                #pragma unroll
                for (int n = 0; n < 4; n++)
                    acc[m][n] = __builtin_amdgcn_mfma_f32_16x16x32_bf16(
                        af[ks][m], bf[ks][n], acc[m][n], 0, 0, 0);
    }

    // epilogue: bits + degree
    #pragma unroll
    for (int m = 0; m < 4; m++) {
        int rbase = j0 + wm * 64 + m * 16 + kg * 4;
        #pragma unroll
        for (int r = 0; r < 4; r++) {
            int row = rbase + r;
            int cnt = 0;
            #pragma unroll
            for (int n = 0; n < 4; n++) {
                int col = c0 + wn * 64 + n * 16 + fr;
                bool bit = (acc[m][n][r] > 0.f) || (row == col);
                MT[(size_t)row * NN + col] = bit ? (unsigned short)0x3F80 : (unsigned short)0;
                cnt += bit ? 1 : 0;
            }
            cnt += __shfl_xor(cnt, 1);
            cnt += __shfl_xor(cnt, 2);
            cnt += __shfl_xor(cnt, 4);
            cnt += __shfl_xor(cnt, 8);
            if (fr == 0) atomicAdd(&deg[row], cnt);
        }
    }
}

__global__ void k_dinv(const int* __restrict__ deg, float* __restrict__ dinv) {
    int i = blockIdx.x * 256 + threadIdx.x;
    if (i < NN) dinv[i] = 1.0f / sqrtf((float)deg[i]);
}

// ---------------- YT[c=b*128+f][i] = bf16( dinv_i * (x[b,i,:] @ W1[:,f]) ) ----------------
__global__ __launch_bounds__(256) void k_y1(
    const float* __restrict__ x, const float* __restrict__ W1,
    const float* __restrict__ dinv, unsigned short* __restrict__ YT)
{
    __shared__ __align__(16) float xs[128][DIN];
    __shared__ __align__(16) float w1s[DIN][DH];
    int i0 = blockIdx.x * 128, b = blockIdx.y;
    int tid = threadIdx.x;
    const f32x4* xg = (const f32x4*)(x + ((size_t)(b * NN + i0)) * DIN);
    #pragma unroll
    for (int q = 0; q < 8; q++) {
        int idx = q * 256 + tid;
        int row = idx >> 4, c4 = idx & 15;
        *(f32x4*)&xs[row][c4 * 4] = xg[(size_t)row * 16 + c4];
    }
    #pragma unroll
    for (int q = 0; q < 8; q++) {
        int idx = q * 256 + tid;
        int row = idx >> 5, c4 = idx & 31;
        *(f32x4*)&w1s[row][c4 * 4] = ((const f32x4*)W1)[idx];
    }
    __syncthreads();
    int tf = tid & 15, ti = tid >> 4;
    f32x4 t0[8] = {}, t1[8] = {};
    for (int k4 = 0; k4 < DIN; k4 += 4) {
        f32x4 xv[8];
        #pragma unroll
        for (int ii = 0; ii < 8; ii++) xv[ii] = *(const f32x4*)&xs[ti * 8 + ii][k4];
        #pragma unroll
        for (int kk = 0; kk < 4; kk++) {
            f32x4 w0 = *(const f32x4*)&w1s[k4 + kk][tf * 8];
            f32x4 w1v = *(const f32x4*)&w1s[k4 + kk][tf * 8 + 4];
            #pragma unroll
            for (int ii = 0; ii < 8; ii++) {
                float s = xv[ii][kk];
                t0[ii] += s * w0;
                t1[ii] += s * w1v;
            }
        }
    }
    float dvv[8];
    #pragma unroll
    for (int ii = 0; ii < 8; ii++) dvv[ii] = dinv[i0 + ti * 8 + ii];
    #pragma unroll
    for (int ff = 0; ff < 8; ff++) {
        s16x8 pk;
        #pragma unroll
        for (int ii = 0; ii < 8; ii++) {
            float v = (ff < 4 ? t0[ii][ff] : t1[ii][ff - 4]) * dvv[ii];
            pk[ii] = (short)f2bf(v);
        }
        *(s16x8*)(YT + ((size_t)(b * DH + tf * 8 + ff)) * NN + i0 + ti * 8) = pk;
    }
}

// ======== gemm1: 256x256, BK=64, 8 waves; deep staging + balanced 8/8/8/0 reads ========
__global__ __launch_bounds__(512, 2) void gemm8(
    const unsigned short* __restrict__ A, const unsigned short* __restrict__ Bt,
    unsigned short* __restrict__ H, const float* __restrict__ dinv,
    const float* __restrict__ bias)
{
    constexpr int K = NN;          // 4096
    constexpr int NT = K / 64;     // 64 K-tiles
    __shared__ __align__(16) unsigned short As[2][256 * 64];   // 64 KB
    __shared__ __align__(16) unsigned short Bs[2][256 * 64];   // 64 KB

    const int tid = threadIdx.x;
    const int lane = tid & 63;
    const int w = tid >> 6;                 // wave 0..7
    const int wm = w >> 2, wn = w & 3;      // 2 x 4 wave grid
    const int fr = lane & 15, kg = lane >> 4;

    const int bid = blockIdx.x;             // 256 blocks -> XCD swizzle
    const int swz = (bid & 7) * 32 + (bid >> 3);
    const int bx = swz & 15, by = swz >> 4;
    const int c0 = bx * 256, j0 = by * 256;

    const int cid0 = w * 128 + lane, cid1 = cid0 + 64;
    const int r0 = cid0 >> 3, k0c = cid0 & 7;
    const int r1 = cid1 >> 3, k1c = cid1 & 7;
    const int so0 = r0 * K + ((k0c ^ (r0 & 7)) << 3);   // ushort units
    const int so1 = r1 * K + ((k1c ^ (r1 & 7)) << 3);
    const int lb0 = (w * 2 + 0) * 512;                  // ushort units
    const int lb1 = (w * 2 + 1) * 512;

    const unsigned short* Aj = A + (size_t)j0 * K;
    const unsigned short* Bc = Bt + (size_t)c0 * K;

#define STAGE_A(buf, half, kt) do { \
    const unsigned short* g_ = Aj + (size_t)((half) * 128) * K + (kt); \
    gload16(g_ + so0, &As[buf][(half) * 8192 + lb0]); \
    gload16(g_ + so1, &As[buf][(half) * 8192 + lb1]); } while (0)
#define STAGE_B(buf, half, kt) do { \
    const unsigned short* g_ = Bc + (size_t)((half) * 128) * K + (kt); \
    gload16(g_ + so0, &Bs[buf][(half) * 8192 + lb0]); \
    gload16(g_ + so1, &Bs[buf][(half) * 8192 + lb1]); } while (0)

    // prologue: tile0 complete (8) + tile1 {Ah0, Ah1, Bh0} (6)
    STAGE_A(0, 0, 0);  STAGE_A(0, 1, 0);
    STAGE_B(0, 0, 0);  STAGE_B(0, 1, 0);
    STAGE_A(1, 0, 64); STAGE_A(1, 1, 64);
    STAGE_B(1, 0, 64);
    asm volatile("s_waitcnt vmcnt(6)" ::: "memory");   // tile0's 8 landed
    bar();

    const int x0 = ((kg) ^ (fr & 7)) << 4;        // ks0 chunk, bytes
    const int x1 = ((4 + kg) ^ (fr & 7)) << 4;    // ks1 chunk, bytes
    int aOff[8], bOff[4];
    #pragma unroll
    for (int m = 0; m < 8; m++) aOff[m] = (wm * 128 + m * 16 + fr) * 128;
    #pragma unroll
    for (int n = 0; n < 4; n++) bOff[n] = (wn * 64 + n * 16 + fr) * 128;

    f32x4 acc[8][4] = {};

    for (int t = 0; t < NT; t++) {
        const int b = t & 1;
        const char* Ab = (const char*)As[b];
        const char* Bb = (const char*)Bs[b];
        const int kt1 = (t + 1) * 64, kt2 = (t + 2) * 64;
        const bool s1 = (t + 1) < NT, s2 = (t + 2) < NT;
        s16x8 af0[8], af1[8], bf0[4], bf1[4];

        // ---- P0: read af0.lo + bf0 (8); stage B(t+1)h1; mfma ks0 m0-3
        #pragma unroll
        for (int m = 0; m < 4; m++) af0[m] = *(const s16x8*)(Ab + aOff[m] + x0);
        #pragma unroll
        for (int n = 0; n < 4; n++) bf0[n] = *(const s16x8*)(Bb + bOff[n] + x0);
        if (s1) STAGE_B(b ^ 1, 1, kt1);
        bar();
        __builtin_amdgcn_s_setprio(1);
        #pragma unroll
        for (int m = 0; m < 4; m++)
            #pragma unroll
            for (int n = 0; n < 4; n++)
                acc[m][n] = __builtin_amdgcn_mfma_f32_16x16x32_bf16(af0[m], bf0[n], acc[m][n], 0, 0, 0);
        __builtin_amdgcn_s_setprio(0);
        bar();

        // ---- P1: read af0.hi + af1.lo (8); mfma ks0 m4-7
        #pragma unroll
        for (int m = 4; m < 8; m++) af0[m] = *(const s16x8*)(Ab + aOff[m] + x0);
        #pragma unroll
        for (int m = 0; m < 4; m++) af1[m] = *(const s16x8*)(Ab + aOff[m] + x1);
        bar();
        __builtin_amdgcn_s_setprio(1);
        #pragma unroll
        for (int m = 4; m < 8; m++)
            #pragma unroll
            for (int n = 0; n < 4; n++)
                acc[m][n] = __builtin_amdgcn_mfma_f32_16x16x32_bf16(af0[m], bf0[n], acc[m][n], 0, 0, 0);
        __builtin_amdgcn_s_setprio(0);
        bar();

        // ---- P2: read af1.hi + bf1 (8); mfma ks1 m0-3
        #pragma unroll
        for (int m = 4; m < 8; m++) af1[m] = *(const s16x8*)(Ab + aOff[m] + x1);
        #pragma unroll
        for (int n = 0; n < 4; n++) bf1[n] = *(const s16x8*)(Bb + bOff[n] + x1);
        bar();
        __builtin_amdgcn_s_setprio(1);
        #pragma unroll
        for (int m = 0; m < 4; m++)
            #pragma unroll
            for (int n = 0; n < 4; n++)
                acc[m][n] = __builtin_amdgcn_mfma_f32_16x16x32_bf16(af1[m], bf1[n], acc[m][n], 0, 0, 0);
        __builtin_amdgcn_s_setprio(0);
        bar();

        // ---- P3: stage A(t+2)h0, A(t+2)h1, B(t+2)h0; vmcnt(6); mfma ks1 m4-7
        if (s2) {
            STAGE_A(b, 0, kt2);
            STAGE_A(b, 1, kt2);
            STAGE_B(b, 0, kt2);
            asm volatile("s_waitcnt vmcnt(6)" ::: "memory");
        } else {
            asm volatile("s_waitcnt vmcnt(0)" ::: "memory");
        }
        bar();
        __builtin_amdgcn_s_setprio(1);
        #pragma unroll
        for (int m = 4; m < 8; m++)
            #pragma unroll
            for (int n = 0; n < 4; n++)
                acc[m][n] = __builtin_amdgcn_mfma_f32_16x16x32_bf16(af1[m], bf1[n], acc[m][n], 0, 0, 0);
        __builtin_amdgcn_s_setprio(0);
        bar();
    }
#undef STAGE_A
#undef STAGE_B

    // epilogue: row = (lane>>4)*4 + r, col = lane&15 per 16x16 frag
    #pragma unroll
    for (int m = 0; m < 8; m++) {
        int rbase = j0 + wm * 128 + m * 16 + kg * 4;
        float dv[4];
        #pragma unroll
        for (int r = 0; r < 4; r++) dv[r] = dinv[rbase + r];
        #pragma unroll
        for (int n = 0; n < 4; n++) {
            int gcol = c0 + wn * 64 + n * 16 + fr;
            float bb = bias[gcol & (DH - 1)];
            #pragma unroll
            for (int r = 0; r < 4; r++) {
                float v = acc[m][n][r] * dv[r] + bb;
                v = v > 0.f ? v : 0.f;
                H[(size_t)(rbase + r) * NN + gcol] = f2bf(v);
            }
        }
    }
}

// ---------- gemm2 (128x128) with FUSED softmax epilogue -> writes out directly ----------
__global__ __launch_bounds__(256) void gemm_sm(
    const unsigned short* __restrict__ A, const unsigned short* __restrict__ Bt,
    float* __restrict__ out, const float* __restrict__ dinv,
    const float* __restrict__ bias, int K)
{
    constexpr int BK = 64;
    __shared__ __align__(16) unsigned short Asm[128 * BK];
    __shared__ __align__(16) unsigned short Bsm[128 * BK];
    const int tid = threadIdx.x;
    const int lane = tid & 63;
    const int w = tid >> 6;
    const int wm = w >> 1, wn = w & 1;
    const int c0 = blockIdx.x * 128;
    const int j0 = blockIdx.y * 128;

    int srcOff[4];
    #pragma unroll
    for (int q = 0; q < 4; q++) {
        int cid = w * 256 + q * 64 + lane;
        int row = cid >> 3, kc = cid & 7;
        srcOff[q] = row * K + ((kc ^ (row & 7)) << 3);
    }
    const int fr = lane & 15;
    const int kg = lane >> 4;

    f32x4 acc[4][4] = {};
    const unsigned short* Abase = A + (size_t)j0 * K;
    const unsigned short* Bbase = Bt + (size_t)c0 * K;

    for (int kt = 0; kt < K; kt += BK) {
        __syncthreads();
        const unsigned short* Ag = Abase + kt;
        const unsigned short* Bg = Bbase + kt;
        #pragma unroll
        for (int q = 0; q < 4; q++)
            gload16(Ag + srcOff[q], &Asm[(w * 256 + q * 64) * 8]);
        #pragma unroll
        for (int q = 0; q < 4; q++)
            gload16(Bg + srcOff[q], &Bsm[(w * 256 + q * 64) * 8]);
        __syncthreads();

        s16x8 af[2][4], bf[2][4];
        #pragma unroll
        for (int ks = 0; ks < 2; ks++) {
            int kc = ks * 4 + kg;
            #pragma unroll
            for (int m = 0; m < 4; m++) {
                int row = wm * 64 + m * 16 + fr;
                af[ks][m] = *(const s16x8*)((const char*)Asm + row * 128 + ((kc ^ (row & 7)) << 4));
            }
            #pragma unroll
            for (int n = 0; n < 4; n++) {
                int row = wn * 64 + n * 16 + fr;
                bf[ks][n] = *(const s16x8*)((const char*)Bsm + row * 128 + ((kc ^ (row & 7)) << 4));
            }
        }
        #pragma unroll
        for (int ks = 0; ks < 2; ks++)
            #pragma unroll
            for (int m = 0; m < 4; m++)
                #pragma unroll
                for (int n = 0; n < 4; n++)
                    acc[m][n] = __builtin_amdgcn_mfma_f32_16x16x32_bf16(
                        af[ks][m], bf[ks][n], acc[m][n], 0, 0, 0);
    }

    // fused epilogue: g = fr (n even) / fr+16 (n odd); batch = (c0>>5) + wn*2 + (n>>1)
    const float b_lo = bias[fr], b_hi = bias[fr + 16];
    #pragma unroll
    for (int m = 0; m < 4; m++) {
        int rbase = j0 + wm * 64 + m * 16 + kg * 4;
        float dv[4];
        #pragma unroll
        for (int r = 0; r < 4; r++) dv[r] = dinv[rbase + r];
        #pragma unroll
        for (int np = 0; np < 2; np++) {
            int bg = (c0 >> 5) + wn * 2 + np;       // batch index 0..31
            #pragma unroll
            for (int r = 0; r < 4; r++) {
                int row = rbase + r;                 // node j
                float v0 = acc[m][np * 2][r]     * dv[r] + b_lo;   // g = fr
                float v1 = acc[m][np * 2 + 1][r] * dv[r] + b_hi;   // g = fr+16
                float mx = fmaxf(v0, v1);
                #pragma unroll
                for (int d = 8; d; d >>= 1) mx = fmaxf(mx, __shfl_xor(mx, d));
                float e0 = expf(v0 - mx), e1 = expf(v1 - mx);
                float s = e0 + e1;
                #pragma unroll
                for (int d = 8; d; d >>= 1) s += __shfl_xor(s, d);
                float inv = 1.0f / s;
                size_t ob = ((size_t)bg * NN + row) * DOUT;
                out[ob + fr]      = e0 * inv;
                out[ob + fr + 16] = e1 * inv;
            }
        }
    }
}

// ---------------- ZT[c2=b*32+g][j] = bf16( dinv_j * (h[b,j,:] @ W2[:,g]) ) ----------------
__global__ __launch_bounds__(256) void k_z(
    const unsigned short* __restrict__ H, const float* __restrict__ W2,
    const float* __restrict__ dinv, unsigned short* __restrict__ ZT)
{
    __shared__ __align__(16) unsigned short Hs[128][136];
    __shared__ __align__(16) float w2s[DH][DOUT];
    int j0 = blockIdx.x * 128, b = blockIdx.y;
    int tid = threadIdx.x;
    #pragma unroll
    for (int q = 0; q < 8; q++) {
        int idx = q * 256 + tid;
        int row = idx >> 4, c = idx & 15;
        *(s16x8*)&Hs[row][c * 8] =
            *(const s16x8*)(H + (size_t)(j0 + row) * (NB * DH) + b * DH + c * 8);
    }
    #pragma unroll
    for (int q = 0; q < 4; q++) {
        int idx = q * 256 + tid;
        int row = idx >> 3, c4 = idx & 7;
        *(f32x4*)&w2s[row][c4 * 4] = ((const f32x4*)W2)[idx];
    }
    __syncthreads();
    int g = tid & 31, jq = tid >> 5;
    #pragma unroll
    for (int t = 0; t < 2; t++) {
        int jb = (t * 8 + jq) * 8;
        float accz[8] = {};
        for (int f8 = 0; f8 < 16; f8++) {
            float wv[8];
            #pragma unroll
            for (int e = 0; e < 8; e++) wv[e] = w2s[f8 * 8 + e][g];
            #pragma unroll
            for (int jj = 0; jj < 8; jj++) {
                s16x8 hc = *(const s16x8*)&Hs[jb + jj][f8 * 8];
                #pragma unroll
                for (int e = 0; e < 8; e++)
                    accz[jj] += bf2f((unsigned short)hc[e]) * wv[e];
            }
        }
        s16x8 pk;
        #pragma unroll
        for (int jj = 0; jj < 8; jj++)
            pk[jj] = (short)f2bf(accz[jj] * dinv[j0 + jb + jj]);
        *(s16x8*)(ZT + (size_t)(b * DOUT + g) * NN + j0 + jb) = pk;
    }
}

extern "C" void kernel_launch(void* const* d_in, const int* in_sizes, int n_in,
                              void* d_out, int out_size, void* d_ws, size_t ws_size,
                              hipStream_t stream)
{
    (void)in_sizes; (void)n_in; (void)out_size; (void)ws_size;
    const float* x    = (const float*)d_in[0];
    const float* emb1 = (const float*)d_in[1];
    const float* emb2 = (const float*)d_in[2];
    const float* l1w  = (const float*)d_in[3];
    const float* l1b  = (const float*)d_in[4];
    const float* l2w  = (const float*)d_in[5];
    const float* l2b  = (const float*)d_in[6];
    const float* g1w  = (const float*)d_in[7];
    const float* g1b  = (const float*)d_in[8];
    const float* g2w  = (const float*)d_in[9];
    const float* g2b  = (const float*)d_in[10];
    float* out = (float*)d_out;

    char* w = (char*)d_ws;
    float* n1 = (float*)w;                    w += NN * DIM * 4;
    float* n2 = (float*)w;                    w += NN * DIM * 4;
    int* deg = (int*)w;                       w += NN * 4;
    float* dinv = (float*)w;                  w += NN * 4;
    unsigned short* MT = (unsigned short*)w;  w += (size_t)NN * NN * 2;
    unsigned short* YT = (unsigned short*)w;  w += (size_t)NN * NN * 2;
    unsigned short* H  = (unsigned short*)w;  w += (size_t)NN * NN * 2;
    unsigned short* ZT = (unsigned short*)w;  w += (size_t)(NB * DOUT) * NN * 2;
    // Ux/Vx live in YT's region (dead until k_y1, which runs after gemm_adj)
    unsigned short* Ux = YT;
    unsigned short* Vx = YT + (size_t)NN * KADJ;

    hipMemsetAsync(deg, 0, NN * sizeof(int), stream);
    k_embed<<<1280, 256, 0, stream>>>(emb1, emb2, l1w, l1b, l2w, l2b, n1, n2);
    k_build_uv<<<256, 256, 0, stream>>>(n1, n2, Ux, Vx);
    gemm_adj<<<dim3(32, 32), 256, 0, stream>>>(Vx, Ux, MT, deg);
    k_dinv<<<16, 256, 0, stream>>>(deg, dinv);
    k_y1<<<dim3(32, 32), 256, 0, stream>>>(x, g1w, dinv, YT);
    gemm8<<<256, 512, 0, stream>>>(MT, YT, H, dinv, g1b);
    k_z<<<dim3(32, 32), 256, 0, stream>>>(H, g2w, dinv, ZT);
    gemm_sm<<<dim3(8, 32), 256, 0, stream>>>(MT, ZT, out, dinv, g2b, NN);
}

// Round 7
// 307.666 us; speedup vs baseline: 1.4228x; 1.0558x over previous
//
#include <hip/hip_runtime.h>

typedef float f32x4 __attribute__((ext_vector_type(4)));
typedef short s16x8 __attribute__((ext_vector_type(8)));

#define NN 4096
#define NB 32
#define DIN 64
#define DH 128
#define DOUT 32
#define DIM 40
#define KADJ 512   // 6 split-blocks x 80, zero-padded to 512

__device__ __forceinline__ unsigned short f2bf(float f) {
    unsigned int u = __float_as_uint(f);
    unsigned int r = (u + 0x7FFFu + ((u >> 16) & 1u)) >> 16;
    return (unsigned short)r;
}
__device__ __forceinline__ float bf2f(unsigned short h) {
    return __uint_as_float(((unsigned int)h) << 16);
}
__device__ __forceinline__ void gload16(const void* g, void* l) {
    __builtin_amdgcn_global_load_lds(
        (const __attribute__((address_space(1))) unsigned int*)g,
        (__attribute__((address_space(3))) unsigned int*)l, 16, 0, 0);
}
__device__ __forceinline__ void bar() {
    asm volatile("" ::: "memory");
    __builtin_amdgcn_s_barrier();
    asm volatile("" ::: "memory");
}

// ---------------- stage 1: n1/n2 = tanh(3*(emb @ W + b)) ----------------
__global__ __launch_bounds__(256) void k_embed(
    const float* __restrict__ emb1, const float* __restrict__ emb2,
    const float* __restrict__ l1w, const float* __restrict__ l1b,
    const float* __restrict__ l2w, const float* __restrict__ l2b,
    float* __restrict__ n1, float* __restrict__ n2)
{
    __shared__ float w1s[DIM * DIM], w2s[DIM * DIM], b1s[DIM], b2s[DIM];
    int tid = threadIdx.x;
    for (int i = tid; i < DIM * DIM; i += 256) { w1s[i] = l1w[i]; w2s[i] = l2w[i]; }
    if (tid < DIM) { b1s[tid] = l1b[tid]; b2s[tid] = l2b[tid]; }
    __syncthreads();
    int t = blockIdx.x * 256 + tid;          // < 2*4096*40 = 327680
    int half = t >= NN * DIM;
    int r = t - half * (NN * DIM);
    int i = r / DIM, c = r - i * DIM;
    const float* emb = half ? emb2 : emb1;
    const float* ws  = half ? w2s : w1s;
    float acc = half ? b2s[c] : b1s[c];
    for (int k = 0; k < DIM; k++) acc += emb[i * DIM + k] * ws[k * DIM + c];
    (half ? n2 : n1)[r] = tanhf(3.0f * acc);
}

// ---------------- stage 2a: build split operands for the adjacency GEMM ----------------
// u[i] = (n1[i], -n2[i]) dim 80; v[j] = (n2[j], n1[j]) dim 80; a[i][j] = u[i]·v[j].
// 3-way bf16 split u = u0+u1+u2; keep 6 cross blocks {00,01,10,11,02,20}
// (dropped 12/21/22 ~ 1.5e-7 ~ f32 noise). K = 6*80 = 480, padded to 512.
__global__ __launch_bounds__(256) void k_build_uv(
    const float* __restrict__ n1, const float* __restrict__ n2,
    unsigned short* __restrict__ Ux, unsigned short* __restrict__ Vx)
{
    __shared__ unsigned short Ul[16][KADJ], Vl[16][KADJ];
    const int tid = threadIdx.x;
    const int r = tid >> 4;                 // local node 0..15
    const int node = blockIdx.x * 16 + r;
    const int k0 = (tid & 15) * 5;          // 5 k's per thread (80 total)
    const int PMAP[6] = {0, 0, 1, 1, 0, 2};
    const int QMAP[6] = {0, 1, 0, 1, 2, 0};
    #pragma unroll
    for (int e = 0; e < 5; e++) {
        int k = k0 + e;
        float a = (k < DIM) ? n1[node * DIM + k] : -n2[node * DIM + k - DIM];
        float b = (k < DIM) ? n2[node * DIM + k] : n1[node * DIM + k - DIM];
        unsigned short u0 = f2bf(a); float ra = a - bf2f(u0);
        unsigned short u1 = f2bf(ra); ra -= bf2f(u1);
        unsigned short u2 = f2bf(ra);
        unsigned short v0 = f2bf(b); float rb = b - bf2f(v0);
        unsigned short v1 = f2bf(rb); rb -= bf2f(v1);
        unsigned short v2 = f2bf(rb);
        unsigned short uu[3] = {u0, u1, u2}, vv[3] = {v0, v1, v2};
        #pragma unroll
        for (int bq = 0; bq < 6; bq++) {
            Ul[r][80 * bq + k] = uu[PMAP[bq]];
            Vl[r][80 * bq + k] = vv[QMAP[bq]];
        }
    }
    {   // zero-pad 480..511 (32 per row, 2 per thread)
        int c = tid & 15;
        Ul[r][480 + c * 2]     = 0; Vl[r][480 + c * 2]     = 0;
        Ul[r][480 + c * 2 + 1] = 0; Vl[r][480 + c * 2 + 1] = 0;
    }
    __syncthreads();
    #pragma unroll
    for (int q = 0; q < 4; q++) {           // 16*512/8 = 1024 chunks
        int idx = q * 256 + tid;
        int rr = idx >> 6, c8 = idx & 63;
        size_t off = ((size_t)(blockIdx.x * 16 + rr)) * KADJ + c8 * 8;
        *(s16x8*)(Ux + off) = *(s16x8*)&Ul[rr][c8 * 8];
        *(s16x8*)(Vx + off) = *(s16x8*)&Vl[rr][c8 * 8];
    }
}

// ---------------- stage 2b: adjacency GEMM -> MT bits (bf16) + deg ----------------
__global__ __launch_bounds__(256) void gemm_adj(
    const unsigned short* __restrict__ V, const unsigned short* __restrict__ U,
    unsigned short* __restrict__ MT, int* __restrict__ deg)
{
    constexpr int K = KADJ;
    constexpr int BK = 64;
    __shared__ __align__(16) unsigned short Asm[128 * BK];
    __shared__ __align__(16) unsigned short Bsm[128 * BK];
    const int tid = threadIdx.x;
    const int lane = tid & 63;
    const int w = tid >> 6;
    const int wm = w >> 1, wn = w & 1;
    const int c0 = blockIdx.x * 128;   // i (cols)
    const int j0 = blockIdx.y * 128;   // j (rows)

    int srcOff[4];
    #pragma unroll
    for (int q = 0; q < 4; q++) {
        int cid = w * 256 + q * 64 + lane;
        int row = cid >> 3, kc = cid & 7;
        srcOff[q] = row * K + ((kc ^ (row & 7)) << 3);
    }
    const int fr = lane & 15;
    const int kg = lane >> 4;

    f32x4 acc[4][4] = {};
    const unsigned short* Abase = V + (size_t)j0 * K;
    const unsigned short* Bbase = U + (size_t)c0 * K;

    for (int kt = 0; kt < K; kt += BK) {
        __syncthreads();
        const unsigned short* Ag = Abase + kt;
        const unsigned short* Bg = Bbase + kt;
        #pragma unroll
        for (int q = 0; q < 4; q++)
            gload16(Ag + srcOff[q], &Asm[(w * 256 + q * 64) * 8]);
        #pragma unroll
        for (int q = 0; q < 4; q++)
            gload16(Bg + srcOff[q], &Bsm[(w * 256 + q * 64) * 8]);
        __syncthreads();

        s16x8 af[2][4], bf[2][4];
        #pragma unroll
        for (int ks = 0; ks < 2; ks++) {
            int kc = ks * 4 + kg;
            #pragma unroll
            for (int m = 0; m < 4; m++) {
                int row = wm * 64 + m * 16 + fr;
                af[ks][m] = *(const s16x8*)((const char*)Asm + row * 128 + ((kc ^ (row & 7)) << 4));
            }
            #pragma unroll
            for (int n = 0; n < 4; n++) {
                int row = wn * 64 + n * 16 + fr;
                bf[ks][n] = *(const s16x8*)((const char*)Bsm + row * 128 + ((kc ^ (row & 7)) << 4));
            }
        }
        #pragma unroll
        for (int ks = 0; ks < 2; ks++)
            #pragma unroll
            for (int m = 0; m < 4; m++)
                #pragma unroll
                for (int n = 0; n < 4; n++)
                    acc[m][n] = __builtin_amdgcn_mfma_f32_16x16x32_bf16(
                        af[ks][m], bf[ks][n], acc[m][n], 0, 0, 0);
    }

    // epilogue: bits + degree
    #pragma unroll
    for (int m = 0; m < 4; m++) {
        int rbase = j0 + wm * 64 + m * 16 + kg * 4;
        #pragma unroll
        for (int r = 0; r < 4; r++) {
            int row = rbase + r;
            int cnt = 0;
            #pragma unroll
            for (int n = 0; n < 4; n++) {
                int col = c0 + wn * 64 + n * 16 + fr;
                bool bit = (acc[m][n][r] > 0.f) || (row == col);
                MT[(size_t)row * NN + col] = bit ? (unsigned short)0x3F80 : (unsigned short)0;
                cnt += bit ? 1 : 0;
            }
            cnt += __shfl_xor(cnt, 1);
            cnt += __shfl_xor(cnt, 2);
            cnt += __shfl_xor(cnt, 4);
            cnt += __shfl_xor(cnt, 8);
            if (fr == 0) atomicAdd(&deg[row], cnt);
        }
    }
}

__global__ void k_dinv(const int* __restrict__ deg, float* __restrict__ dinv) {
    int i = blockIdx.x * 256 + threadIdx.x;
    if (i < NN) dinv[i] = 1.0f / sqrtf((float)deg[i]);
}

// ---------------- YT[c=b*128+f][i] = bf16( dinv_i * (x[b,i,:] @ W1[:,f]) ) ----------------
__global__ __launch_bounds__(256) void k_y1(
    const float* __restrict__ x, const float* __restrict__ W1,
    const float* __restrict__ dinv, unsigned short* __restrict__ YT)
{
    __shared__ __align__(16) float xs[128][DIN];
    __shared__ __align__(16) float w1s[DIN][DH];
    int i0 = blockIdx.x * 128, b = blockIdx.y;
    int tid = threadIdx.x;
    const f32x4* xg = (const f32x4*)(x + ((size_t)(b * NN + i0)) * DIN);
    #pragma unroll
    for (int q = 0; q < 8; q++) {
        int idx = q * 256 + tid;
        int row = idx >> 4, c4 = idx & 15;
        *(f32x4*)&xs[row][c4 * 4] = xg[(size_t)row * 16 + c4];
    }
    #pragma unroll
    for (int q = 0; q < 8; q++) {
        int idx = q * 256 + tid;
        int row = idx >> 5, c4 = idx & 31;
        *(f32x4*)&w1s[row][c4 * 4] = ((const f32x4*)W1)[idx];
    }
    __syncthreads();
    int tf = tid & 15, ti = tid >> 4;
    f32x4 t0[8] = {}, t1[8] = {};
    for (int k4 = 0; k4 < DIN; k4 += 4) {
        f32x4 xv[8];
        #pragma unroll
        for (int ii = 0; ii < 8; ii++) xv[ii] = *(const f32x4*)&xs[ti * 8 + ii][k4];
        #pragma unroll
        for (int kk = 0; kk < 4; kk++) {
            f32x4 w0 = *(const f32x4*)&w1s[k4 + kk][tf * 8];
            f32x4 w1v = *(const f32x4*)&w1s[k4 + kk][tf * 8 + 4];
            #pragma unroll
            for (int ii = 0; ii < 8; ii++) {
                float s = xv[ii][kk];
                t0[ii] += s * w0;
                t1[ii] += s * w1v;
            }
        }
    }
    float dvv[8];
    #pragma unroll
    for (int ii = 0; ii < 8; ii++) dvv[ii] = dinv[i0 + ti * 8 + ii];
    #pragma unroll
    for (int ff = 0; ff < 8; ff++) {
        s16x8 pk;
        #pragma unroll
        for (int ii = 0; ii < 8; ii++) {
            float v = (ff < 4 ? t0[ii][ff] : t1[ii][ff - 4]) * dvv[ii];
            pk[ii] = (short)f2bf(v);
        }
        *(s16x8*)(YT + ((size_t)(b * DH + tf * 8 + ff)) * NN + i0 + ti * 8) = pk;
    }
}

// ======== gemm1: 256x256, BK=64, 8 waves; 2 barriers/K-tile + phase read-ahead ========
// Tile t lives in buffer P=t&1. Per K-tile:
//  A: read af0hi+af1lo(P); stage B(t+1)h1->P^1;          MFMA ks0 m0-3 (carried frags)
//  B: read af1hi+bf1(P);                                 MFMA ks0 m4-7; lgkmcnt(0); BAR
//  C: MFMA ks1 m0-3; stage A(t+2)h0,h1,B(t+2)h0 -> P (reads of P drained at BAR);
//     vmcnt(6) [drains exactly tile t+1]; BAR [cross-wave visibility]
//  D: read-ahead af0c',bf0c' of tile t+1 from P^1;       MFMA ks1 m4-7
__global__ __launch_bounds__(512, 2) void gemm8(
    const unsigned short* __restrict__ A, const unsigned short* __restrict__ Bt,
    unsigned short* __restrict__ H, const float* __restrict__ dinv,
    const float* __restrict__ bias)
{
    constexpr int K = NN;          // 4096
    constexpr int NT = K / 64;     // 64 K-tiles
    __shared__ __align__(16) unsigned short As[2][256 * 64];   // 64 KB
    __shared__ __align__(16) unsigned short Bs[2][256 * 64];   // 64 KB

    const int tid = threadIdx.x;
    const int lane = tid & 63;
    const int w = tid >> 6;                 // wave 0..7
    const int wm = w >> 2, wn = w & 3;      // 2 x 4 wave grid
    const int fr = lane & 15, kg = lane >> 4;

    const int bid = blockIdx.x;             // 256 blocks -> XCD swizzle
    const int swz = (bid & 7) * 32 + (bid >> 3);
    const int bx = swz & 15, by = swz >> 4;
    const int c0 = bx * 256, j0 = by * 256;

    const int cid0 = w * 128 + lane, cid1 = cid0 + 64;
    const int r0 = cid0 >> 3, k0c = cid0 & 7;
    const int r1 = cid1 >> 3, k1c = cid1 & 7;
    const int so0 = r0 * K + ((k0c ^ (r0 & 7)) << 3);   // ushort units
    const int so1 = r1 * K + ((k1c ^ (r1 & 7)) << 3);
    const int lb0 = (w * 2 + 0) * 512;                  // ushort units
    const int lb1 = (w * 2 + 1) * 512;

    const unsigned short* Aj = A + (size_t)j0 * K;
    const unsigned short* Bc = Bt + (size_t)c0 * K;

#define STAGE_A(buf, half, kt) do { \
    const unsigned short* g_ = Aj + (size_t)((half) * 128) * K + (kt); \
    gload16(g_ + so0, &As[buf][(half) * 8192 + lb0]); \
    gload16(g_ + so1, &As[buf][(half) * 8192 + lb1]); } while (0)
#define STAGE_B(buf, half, kt) do { \
    const unsigned short* g_ = Bc + (size_t)((half) * 128) * K + (kt); \
    gload16(g_ + so0, &Bs[buf][(half) * 8192 + lb0]); \
    gload16(g_ + so1, &Bs[buf][(half) * 8192 + lb1]); } while (0)

    // prologue: tile0 complete (8) + tile1 {Ah0, Ah1, Bh0} (6)
    STAGE_A(0, 0, 0);  STAGE_A(0, 1, 0);
    STAGE_B(0, 0, 0);  STAGE_B(0, 1, 0);
    STAGE_A(1, 0, 64); STAGE_A(1, 1, 64);
    STAGE_B(1, 0, 64);
    asm volatile("s_waitcnt vmcnt(6)" ::: "memory");   // tile0's 8 landed
    bar();

    const int x0 = ((kg) ^ (fr & 7)) << 4;        // ks0 chunk, bytes
    const int x1 = ((4 + kg) ^ (fr & 7)) << 4;    // ks1 chunk, bytes
    int aOff[8], bOff[4];
    #pragma unroll
    for (int m = 0; m < 8; m++) aOff[m] = (wm * 128 + m * 16 + fr) * 128;
    #pragma unroll
    for (int n = 0; n < 4; n++) bOff[n] = (wn * 64 + n * 16 + fr) * 128;

    // read-ahead tile0's ks0-lo A frags + ks0 B frags
    s16x8 af0c[4], bf0c[4];
    #pragma unroll
    for (int m = 0; m < 4; m++) af0c[m] = *(const s16x8*)((const char*)As[0] + aOff[m] + x0);
    #pragma unroll
    for (int n = 0; n < 4; n++) bf0c[n] = *(const s16x8*)((const char*)Bs[0] + bOff[n] + x0);

    f32x4 acc[8][4] = {};

    for (int t = 0; t < NT; t++) {
        const int P = t & 1;
        const char* Ap = (const char*)As[P];
        const char* Bp = (const char*)Bs[P];
        const char* Aq = (const char*)As[P ^ 1];
        const char* Bq = (const char*)Bs[P ^ 1];
        const int kt1 = (t + 1) * 64, kt2 = (t + 2) * 64;
        const bool s1 = (t + 1) < NT, s2 = (t + 2) < NT;
        s16x8 af0h[4], af1l[4], af1h[4], bf1[4], af0n[4], bf0n[4];

        // ---- phase A: reads (8) + stage B(t+1)h1 + MFMA ks0 m0-3 (carried frags)
        #pragma unroll
        for (int m = 0; m < 4; m++) af0h[m] = *(const s16x8*)(Ap + aOff[m + 4] + x0);
        #pragma unroll
        for (int m = 0; m < 4; m++) af1l[m] = *(const s16x8*)(Ap + aOff[m] + x1);
        if (s1) STAGE_B(P ^ 1, 1, kt1);
        __builtin_amdgcn_s_setprio(1);
        #pragma unroll
        for (int m = 0; m < 4; m++)
            #pragma unroll
            for (int n = 0; n < 4; n++)
                acc[m][n] = __builtin_amdgcn_mfma_f32_16x16x32_bf16(af0c[m], bf0c[n], acc[m][n], 0, 0, 0);
        __builtin_amdgcn_s_setprio(0);

        // ---- phase B: reads (8) + MFMA ks0 m4-7; drain own reads; BAR(i)
        #pragma unroll
        for (int m = 0; m < 4; m++) af1h[m] = *(const s16x8*)(Ap + aOff[m + 4] + x1);
        #pragma unroll
        for (int n = 0; n < 4; n++) bf1[n] = *(const s16x8*)(Bp + bOff[n] + x1);
        __builtin_amdgcn_s_setprio(1);
        #pragma unroll
        for (int m = 4; m < 8; m++)
            #pragma unroll
            for (int n = 0; n < 4; n++)
                acc[m][n] = __builtin_amdgcn_mfma_f32_16x16x32_bf16(af0h[m - 4], bf0c[n], acc[m][n], 0, 0, 0);
        __builtin_amdgcn_s_setprio(0);
        asm volatile("s_waitcnt lgkmcnt(0)" ::: "memory");
        bar();                                   // BAR(i): all waves' P-reads serviced

        // ---- phase C: MFMA ks1 m0-3 + stage t+2 into P + counted vmcnt + BAR(ii)
        __builtin_amdgcn_s_setprio(1);
        #pragma unroll
        for (int m = 0; m < 4; m++)
            #pragma unroll
            for (int n = 0; n < 4; n++)
                acc[m][n] = __builtin_amdgcn_mfma_f32_16x16x32_bf16(af1l[m], bf1[n], acc[m][n], 0, 0, 0);
        __builtin_amdgcn_s_setprio(0);
        if (s2) {
            STAGE_A(P, 0, kt2);
            STAGE_A(P, 1, kt2);
            STAGE_B(P, 0, kt2);
            asm volatile("s_waitcnt vmcnt(6)" ::: "memory");   // tile t+1 fully landed
        } else {
            asm volatile("s_waitcnt vmcnt(0)" ::: "memory");
        }
        bar();                                   // BAR(ii): cross-wave load visibility

        // ---- phase D: read-ahead tile t+1 ks0 frags + MFMA ks1 m4-7
        if (s1) {
            #pragma unroll
            for (int m = 0; m < 4; m++) af0n[m] = *(const s16x8*)(Aq + aOff[m] + x0);
            #pragma unroll
            for (int n = 0; n < 4; n++) bf0n[n] = *(const s16x8*)(Bq + bOff[n] + x0);
        }
        __builtin_amdgcn_s_setprio(1);
        #pragma unroll
        for (int m = 4; m < 8; m++)
            #pragma unroll
            for (int n = 0; n < 4; n++)
                acc[m][n] = __builtin_amdgcn_mfma_f32_16x16x32_bf16(af1h[m - 4], bf1[n], acc[m][n], 0, 0, 0);
        __builtin_amdgcn_s_setprio(0);
        if (s1) {
            #pragma unroll
            for (int m = 0; m < 4; m++) af0c[m] = af0n[m];
            #pragma unroll
            for (int n = 0; n < 4; n++) bf0c[n] = bf0n[n];
        }
    }
#undef STAGE_A
#undef STAGE_B

    // epilogue: row = (lane>>4)*4 + r, col = lane&15 per 16x16 frag
    #pragma unroll
    for (int m = 0; m < 8; m++) {
        int rbase = j0 + wm * 128 + m * 16 + kg * 4;
        float dv[4];
        #pragma unroll
        for (int r = 0; r < 4; r++) dv[r] = dinv[rbase + r];
        #pragma unroll
        for (int n = 0; n < 4; n++) {
            int gcol = c0 + wn * 64 + n * 16 + fr;
            float bb = bias[gcol & (DH - 1)];
            #pragma unroll
            for (int r = 0; r < 4; r++) {
                float v = acc[m][n][r] * dv[r] + bb;
                v = v > 0.f ? v : 0.f;
                H[(size_t)(rbase + r) * NN + gcol] = f2bf(v);
            }
        }
    }
}

// ---------- gemm2 (128x128) with FUSED softmax epilogue -> writes out directly ----------
__global__ __launch_bounds__(256) void gemm_sm(
    const unsigned short* __restrict__ A, const unsigned short* __restrict__ Bt,
    float* __restrict__ out, const float* __restrict__ dinv,
    const float* __restrict__ bias, int K)
{
    constexpr int BK = 64;
    __shared__ __align__(16) unsigned short Asm[128 * BK];
    __shared__ __align__(16) unsigned short Bsm[128 * BK];
    const int tid = threadIdx.x;
    const int lane = tid & 63;
    const int w = tid >> 6;
    const int wm = w >> 1, wn = w & 1;
    const int c0 = blockIdx.x * 128;
    const int j0 = blockIdx.y * 128;

    int srcOff[4];
    #pragma unroll
    for (int q = 0; q < 4; q++) {
        int cid = w * 256 + q * 64 + lane;
        int row = cid >> 3, kc = cid & 7;
        srcOff[q] = row * K + ((kc ^ (row & 7)) << 3);
    }
    const int fr = lane & 15;
    const int kg = lane >> 4;

    f32x4 acc[4][4] = {};
    const unsigned short* Abase = A + (size_t)j0 * K;
    const unsigned short* Bbase = Bt + (size_t)c0 * K;

    for (int kt = 0; kt < K; kt += BK) {
        __syncthreads();
        const unsigned short* Ag = Abase + kt;
        const unsigned short* Bg = Bbase + kt;
        #pragma unroll
        for (int q = 0; q < 4; q++)
            gload16(Ag + srcOff[q], &Asm[(w * 256 + q * 64) * 8]);
        #pragma unroll
        for (int q = 0; q < 4; q++)
            gload16(Bg + srcOff[q], &Bsm[(w * 256 + q * 64) * 8]);
        __syncthreads();

        s16x8 af[2][4], bf[2][4];
        #pragma unroll
        for (int ks = 0; ks < 2; ks++) {
            int kc = ks * 4 + kg;
            #pragma unroll
            for (int m = 0; m < 4; m++) {
                int row = wm * 64 + m * 16 + fr;
                af[ks][m] = *(const s16x8*)((const char*)Asm + row * 128 + ((kc ^ (row & 7)) << 4));
            }
            #pragma unroll
            for (int n = 0; n < 4; n++) {
                int row = wn * 64 + n * 16 + fr;
                bf[ks][n] = *(const s16x8*)((const char*)Bsm + row * 128 + ((kc ^ (row & 7)) << 4));
            }
        }
        #pragma unroll
        for (int ks = 0; ks < 2; ks++)
            #pragma unroll
            for (int m = 0; m < 4; m++)
                #pragma unroll
                for (int n = 0; n < 4; n++)
                    acc[m][n] = __builtin_amdgcn_mfma_f32_16x16x32_bf16(
                        af[ks][m], bf[ks][n], acc[m][n], 0, 0, 0);
    }

    // fused epilogue: g = fr (n even) / fr+16 (n odd); batch = (c0>>5) + wn*2 + (n>>1)
    const float b_lo = bias[fr], b_hi = bias[fr + 16];
    #pragma unroll
    for (int m = 0; m < 4; m++) {
        int rbase = j0 + wm * 64 + m * 16 + kg * 4;
        float dv[4];
        #pragma unroll
        for (int r = 0; r < 4; r++) dv[r] = dinv[rbase + r];
        #pragma unroll
        for (int np = 0; np < 2; np++) {
            int bg = (c0 >> 5) + wn * 2 + np;       // batch index 0..31
            #pragma unroll
            for (int r = 0; r < 4; r++) {
                int row = rbase + r;                 // node j
                float v0 = acc[m][np * 2][r]     * dv[r] + b_lo;   // g = fr
                float v1 = acc[m][np * 2 + 1][r] * dv[r] + b_hi;   // g = fr+16
                float mx = fmaxf(v0, v1);
                #pragma unroll
                for (int d = 8; d; d >>= 1) mx = fmaxf(mx, __shfl_xor(mx, d));
                float e0 = expf(v0 - mx), e1 = expf(v1 - mx);
                float s = e0 + e1;
                #pragma unroll
                for (int d = 8; d; d >>= 1) s += __shfl_xor(s, d);
                float inv = 1.0f / s;
                size_t ob = ((size_t)bg * NN + row) * DOUT;
                out[ob + fr]      = e0 * inv;
                out[ob + fr + 16] = e1 * inv;
            }
        }
    }
}

// ---------------- ZT[c2=b*32+g][j] = bf16( dinv_j * (h[b,j,:] @ W2[:,g]) ) ----------------
__global__ __launch_bounds__(256) void k_z(
    const unsigned short* __restrict__ H, const float* __restrict__ W2,
    const float* __restrict__ dinv, unsigned short* __restrict__ ZT)
{
    __shared__ __align__(16) unsigned short Hs[128][136];
    __shared__ __align__(16) float w2s[DH][DOUT];
    int j0 = blockIdx.x * 128, b = blockIdx.y;
    int tid = threadIdx.x;
    #pragma unroll
    for (int q = 0; q < 8; q++) {
        int idx = q * 256 + tid;
        int row = idx >> 4, c = idx & 15;
        *(s16x8*)&Hs[row][c * 8] =
            *(const s16x8*)(H + (size_t)(j0 + row) * (NB * DH) + b * DH + c * 8);
    }
    #pragma unroll
    for (int q = 0; q < 4; q++) {
        int idx = q * 256 + tid;
        int row = idx >> 3, c4 = idx & 7;
        *(f32x4*)&w2s[row][c4 * 4] = ((const f32x4*)W2)[idx];
    }
    __syncthreads();
    int g = tid & 31, jq = tid >> 5;
    #pragma unroll
    for (int t = 0; t < 2; t++) {
        int jb = (t * 8 + jq) * 8;
        float accz[8] = {};
        for (int f8 = 0; f8 < 16; f8++) {
            float wv[8];
            #pragma unroll
            for (int e = 0; e < 8; e++) wv[e] = w2s[f8 * 8 + e][g];
            #pragma unroll
            for (int jj = 0; jj < 8; jj++) {
                s16x8 hc = *(const s16x8*)&Hs[jb + jj][f8 * 8];
                #pragma unroll
                for (int e = 0; e < 8; e++)
                    accz[jj] += bf2f((unsigned short)hc[e]) * wv[e];
            }
        }
        s16x8 pk;
        #pragma unroll
        for (int jj = 0; jj < 8; jj++)
            pk[jj] = (short)f2bf(accz[jj] * dinv[j0 + jb + jj]);
        *(s16x8*)(ZT + (size_t)(b * DOUT + g) * NN + j0 + jb) = pk;
    }
}

extern "C" void kernel_launch(void* const* d_in, const int* in_sizes, int n_in,
                              void* d_out, int out_size, void* d_ws, size_t ws_size,
                              hipStream_t stream)
{
    (void)in_sizes; (void)n_in; (void)out_size; (void)ws_size;
    const float* x    = (const float*)d_in[0];
    const float* emb1 = (const float*)d_in[1];
    const float* emb2 = (const float*)d_in[2];
    const float* l1w  = (const float*)d_in[3];
    const float* l1b  = (const float*)d_in[4];
    const float* l2w  = (const float*)d_in[5];
    const float* l2b  = (const float*)d_in[6];
    const float* g1w  = (const float*)d_in[7];
    const float* g1b  = (const float*)d_in[8];
    const float* g2w  = (const float*)d_in[9];
    const float* g2b  = (const float*)d_in[10];
    float* out = (float*)d_out;

    char* w = (char*)d_ws;
    float* n1 = (float*)w;                    w += NN * DIM * 4;
    float* n2 = (float*)w;                    w += NN * DIM * 4;
    int* deg = (int*)w;                       w += NN * 4;
    float* dinv = (float*)w;                  w += NN * 4;
    unsigned short* MT = (unsigned short*)w;  w += (size_t)NN * NN * 2;
    unsigned short* YT = (unsigned short*)w;  w += (size_t)NN * NN * 2;
    unsigned short* H  = (unsigned short*)w;  w += (size_t)NN * NN * 2;
    unsigned short* ZT = (unsigned short*)w;  w += (size_t)(NB * DOUT) * NN * 2;
    // Ux/Vx live in YT's region (dead until k_y1, which runs after gemm_adj)
    unsigned short* Ux = YT;
    unsigned short* Vx = YT + (size_t)NN * KADJ;

    hipMemsetAsync(deg, 0, NN * sizeof(int), stream);
    k_embed<<<1280, 256, 0, stream>>>(emb1, emb2, l1w, l1b, l2w, l2b, n1, n2);
    k_build_uv<<<256, 256, 0, stream>>>(n1, n2, Ux, Vx);
    gemm_adj<<<dim3(32, 32), 256, 0, stream>>>(Vx, Ux, MT, deg);
    k_dinv<<<16, 256, 0, stream>>>(deg, dinv);
    k_y1<<<dim3(32, 32), 256, 0, stream>>>(x, g1w, dinv, YT);
    gemm8<<<256, 512, 0, stream>>>(MT, YT, H, dinv, g1b);
    k_z<<<dim3(32, 32), 256, 0, stream>>>(H, g2w, dinv, ZT);
    gemm_sm<<<dim3(8, 32), 256, 0, stream>>>(MT, ZT, out, dinv, g2b, NN);
}

// Round 8
// 277.308 us; speedup vs baseline: 1.5786x; 1.1095x over previous
//
#include <hip/hip_runtime.h>

typedef float f32x4 __attribute__((ext_vector_type(4)));
typedef short s16x8 __attribute__((ext_vector_type(8)));
typedef short s16x4 __attribute__((ext_vector_type(4)));

#define NN 4096
#define NB 32
#define DIN 64
#define DH 128
#define DOUT 32
#define DIM 40
#define KADJ 512   // 6 split-blocks x 80, zero-padded to 512

__device__ __forceinline__ unsigned short f2bf(float f) {
    unsigned int u = __float_as_uint(f);
    unsigned int r = (u + 0x7FFFu + ((u >> 16) & 1u)) >> 16;
    return (unsigned short)r;
}
__device__ __forceinline__ float bf2f(unsigned short h) {
    return __uint_as_float(((unsigned int)h) << 16);
}
__device__ __forceinline__ void gload16(const void* g, void* l) {
    __builtin_amdgcn_global_load_lds(
        (const __attribute__((address_space(1))) unsigned int*)g,
        (__attribute__((address_space(3))) unsigned int*)l, 16, 0, 0);
}
__device__ __forceinline__ void bar() {
    asm volatile("" ::: "memory");
    __builtin_amdgcn_s_barrier();
    asm volatile("" ::: "memory");
}

// ---------------- stage 1: n1/n2 = tanh(3*(emb @ W + b)) ----------------
__global__ __launch_bounds__(256) void k_embed(
    const float* __restrict__ emb1, const float* __restrict__ emb2,
    const float* __restrict__ l1w, const float* __restrict__ l1b,
    const float* __restrict__ l2w, const float* __restrict__ l2b,
    float* __restrict__ n1, float* __restrict__ n2)
{
    __shared__ float w1s[DIM * DIM], w2s[DIM * DIM], b1s[DIM], b2s[DIM];
    int tid = threadIdx.x;
    for (int i = tid; i < DIM * DIM; i += 256) { w1s[i] = l1w[i]; w2s[i] = l2w[i]; }
    if (tid < DIM) { b1s[tid] = l1b[tid]; b2s[tid] = l2b[tid]; }
    __syncthreads();
    int t = blockIdx.x * 256 + tid;          // < 2*4096*40 = 327680
    int half = t >= NN * DIM;
    int r = t - half * (NN * DIM);
    int i = r / DIM, c = r - i * DIM;
    const float* emb = half ? emb2 : emb1;
    const float* ws  = half ? w2s : w1s;
    float acc = half ? b2s[c] : b1s[c];
    for (int k = 0; k < DIM; k++) acc += emb[i * DIM + k] * ws[k * DIM + c];
    (half ? n2 : n1)[r] = tanhf(3.0f * acc);
}

// ---------------- stage 2a: build split operands for the adjacency GEMM ----------------
__global__ __launch_bounds__(256) void k_build_uv(
    const float* __restrict__ n1, const float* __restrict__ n2,
    unsigned short* __restrict__ Ux, unsigned short* __restrict__ Vx)
{
    __shared__ unsigned short Ul[16][KADJ], Vl[16][KADJ];
    const int tid = threadIdx.x;
    const int r = tid >> 4;                 // local node 0..15
    const int node = blockIdx.x * 16 + r;
    const int k0 = (tid & 15) * 5;          // 5 k's per thread (80 total)
    const int PMAP[6] = {0, 0, 1, 1, 0, 2};
    const int QMAP[6] = {0, 1, 0, 1, 2, 0};
    #pragma unroll
    for (int e = 0; e < 5; e++) {
        int k = k0 + e;
        float a = (k < DIM) ? n1[node * DIM + k] : -n2[node * DIM + k - DIM];
        float b = (k < DIM) ? n2[node * DIM + k] : n1[node * DIM + k - DIM];
        unsigned short u0 = f2bf(a); float ra = a - bf2f(u0);
        unsigned short u1 = f2bf(ra); ra -= bf2f(u1);
        unsigned short u2 = f2bf(ra);
        unsigned short v0 = f2bf(b); float rb = b - bf2f(v0);
        unsigned short v1 = f2bf(rb); rb -= bf2f(v1);
        unsigned short v2 = f2bf(rb);
        unsigned short uu[3] = {u0, u1, u2}, vv[3] = {v0, v1, v2};
        #pragma unroll
        for (int bq = 0; bq < 6; bq++) {
            Ul[r][80 * bq + k] = uu[PMAP[bq]];
            Vl[r][80 * bq + k] = vv[QMAP[bq]];
        }
    }
    {   // zero-pad 480..511
        int c = tid & 15;
        Ul[r][480 + c * 2]     = 0; Vl[r][480 + c * 2]     = 0;
        Ul[r][480 + c * 2 + 1] = 0; Vl[r][480 + c * 2 + 1] = 0;
    }
    __syncthreads();
    #pragma unroll
    for (int q = 0; q < 4; q++) {           // 16*512/8 = 1024 chunks
        int idx = q * 256 + tid;
        int rr = idx >> 6, c8 = idx & 63;
        size_t off = ((size_t)(blockIdx.x * 16 + rr)) * KADJ + c8 * 8;
        *(s16x8*)(Ux + off) = *(s16x8*)&Ul[rr][c8 * 8];
        *(s16x8*)(Vx + off) = *(s16x8*)&Vl[rr][c8 * 8];
    }
}

// ---------------- stage 2b: adjacency GEMM -> MT bits (bf16) + deg ----------------
__global__ __launch_bounds__(256) void gemm_adj(
    const unsigned short* __restrict__ V, const unsigned short* __restrict__ U,
    unsigned short* __restrict__ MT, int* __restrict__ deg)
{
    constexpr int K = KADJ;
    constexpr int BK = 64;
    __shared__ __align__(16) unsigned short Asm[128 * BK];
    __shared__ __align__(16) unsigned short Bsm[128 * BK];
    const int tid = threadIdx.x;
    const int lane = tid & 63;
    const int w = tid >> 6;
    const int wm = w >> 1, wn = w & 1;
    const int c0 = blockIdx.x * 128;   // i (cols)
    const int j0 = blockIdx.y * 128;   // j (rows)

    int srcOff[4];
    #pragma unroll
    for (int q = 0; q < 4; q++) {
        int cid = w * 256 + q * 64 + lane;
        int row = cid >> 3, kc = cid & 7;
        srcOff[q] = row * K + ((kc ^ (row & 7)) << 3);
    }
    const int fr = lane & 15;
    const int kg = lane >> 4;

    f32x4 acc[4][4] = {};
    const unsigned short* Abase = V + (size_t)j0 * K;
    const unsigned short* Bbase = U + (size_t)c0 * K;

    for (int kt = 0; kt < K; kt += BK) {
        __syncthreads();
        const unsigned short* Ag = Abase + kt;
        const unsigned short* Bg = Bbase + kt;
        #pragma unroll
        for (int q = 0; q < 4; q++)
            gload16(Ag + srcOff[q], &Asm[(w * 256 + q * 64) * 8]);
        #pragma unroll
        for (int q = 0; q < 4; q++)
            gload16(Bg + srcOff[q], &Bsm[(w * 256 + q * 64) * 8]);
        __syncthreads();

        s16x8 af[2][4], bf[2][4];
        #pragma unroll
        for (int ks = 0; ks < 2; ks++) {
            int kc = ks * 4 + kg;
            #pragma unroll
            for (int m = 0; m < 4; m++) {
                int row = wm * 64 + m * 16 + fr;
                af[ks][m] = *(const s16x8*)((const char*)Asm + row * 128 + ((kc ^ (row & 7)) << 4));
            }
            #pragma unroll
            for (int n = 0; n < 4; n++) {
                int row = wn * 64 + n * 16 + fr;
                bf[ks][n] = *(const s16x8*)((const char*)Bsm + row * 128 + ((kc ^ (row & 7)) << 4));
            }
        }
        #pragma unroll
        for (int ks = 0; ks < 2; ks++)
            #pragma unroll
            for (int m = 0; m < 4; m++)
                #pragma unroll
                for (int n = 0; n < 4; n++)
                    acc[m][n] = __builtin_amdgcn_mfma_f32_16x16x32_bf16(
                        af[ks][m], bf[ks][n], acc[m][n], 0, 0, 0);
    }

    // epilogue: bits + degree
    #pragma unroll
    for (int m = 0; m < 4; m++) {
        int rbase = j0 + wm * 64 + m * 16 + kg * 4;
        #pragma unroll
        for (int r = 0; r < 4; r++) {
            int row = rbase + r;
            int cnt = 0;
            #pragma unroll
            for (int n = 0; n < 4; n++) {
                int col = c0 + wn * 64 + n * 16 + fr;
                bool bit = (acc[m][n][r] > 0.f) || (row == col);
                MT[(size_t)row * NN + col] = bit ? (unsigned short)0x3F80 : (unsigned short)0;
                cnt += bit ? 1 : 0;
            }
            cnt += __shfl_xor(cnt, 1);
            cnt += __shfl_xor(cnt, 2);
            cnt += __shfl_xor(cnt, 4);
            cnt += __shfl_xor(cnt, 8);
            if (fr == 0) atomicAdd(&deg[row], cnt);
        }
    }
}

__global__ void k_dinv(const int* __restrict__ deg, float* __restrict__ dinv) {
    int i = blockIdx.x * 256 + threadIdx.x;
    if (i < NN) dinv[i] = 1.0f / sqrtf((float)deg[i]);
}

// ---------------- YT[c=b*128+f][i] = bf16( dinv_i * (x[b,i,:] @ W1[:,f]) ) ----------------
__global__ __launch_bounds__(256) void k_y1(
    const float* __restrict__ x, const float* __restrict__ W1,
    const float* __restrict__ dinv, unsigned short* __restrict__ YT)
{
    __shared__ __align__(16) float xs[128][DIN];
    __shared__ __align__(16) float w1s[DIN][DH];
    int i0 = blockIdx.x * 128, b = blockIdx.y;
    int tid = threadIdx.x;
    const f32x4* xg = (const f32x4*)(x + ((size_t)(b * NN + i0)) * DIN);
    #pragma unroll
    for (int q = 0; q < 8; q++) {
        int idx = q * 256 + tid;
        int row = idx >> 4, c4 = idx & 15;
        *(f32x4*)&xs[row][c4 * 4] = xg[(size_t)row * 16 + c4];
    }
    #pragma unroll
    for (int q = 0; q < 8; q++) {
        int idx = q * 256 + tid;
        int row = idx >> 5, c4 = idx & 31;
        *(f32x4*)&w1s[row][c4 * 4] = ((const f32x4*)W1)[idx];
    }
    __syncthreads();
    int tf = tid & 15, ti = tid >> 4;
    f32x4 t0[8] = {}, t1[8] = {};
    for (int k4 = 0; k4 < DIN; k4 += 4) {
        f32x4 xv[8];
        #pragma unroll
        for (int ii = 0; ii < 8; ii++) xv[ii] = *(const f32x4*)&xs[ti * 8 + ii][k4];
        #pragma unroll
        for (int kk = 0; kk < 4; kk++) {
            f32x4 w0 = *(const f32x4*)&w1s[k4 + kk][tf * 8];
            f32x4 w1v = *(const f32x4*)&w1s[k4 + kk][tf * 8 + 4];
            #pragma unroll
            for (int ii = 0; ii < 8; ii++) {
                float s = xv[ii][kk];
                t0[ii] += s * w0;
                t1[ii] += s * w1v;
            }
        }
    }
    float dvv[8];
    #pragma unroll
    for (int ii = 0; ii < 8; ii++) dvv[ii] = dinv[i0 + ti * 8 + ii];
    #pragma unroll
    for (int ff = 0; ff < 8; ff++) {
        s16x8 pk;
        #pragma unroll
        for (int ii = 0; ii < 8; ii++) {
            float v = (ff < 4 ? t0[ii][ff] : t1[ii][ff - 4]) * dvv[ii];
            pk[ii] = (short)f2bf(v);
        }
        *(s16x8*)(YT + ((size_t)(b * DH + tf * 8 + ff)) * NN + i0 + ti * 8) = pk;
    }
}

// ======== gemm1: 256x256, BK=64, 8 waves; 2 barriers/K-tile + phase read-ahead ========
__global__ __launch_bounds__(512, 2) void gemm8(
    const unsigned short* __restrict__ A, const unsigned short* __restrict__ Bt,
    unsigned short* __restrict__ H, const float* __restrict__ dinv,
    const float* __restrict__ bias)
{
    constexpr int K = NN;          // 4096
    constexpr int NT = K / 64;     // 64 K-tiles
    __shared__ __align__(16) unsigned short As[2][256 * 64];   // 64 KB
    __shared__ __align__(16) unsigned short Bs[2][256 * 64];   // 64 KB

    const int tid = threadIdx.x;
    const int lane = tid & 63;
    const int w = tid >> 6;                 // wave 0..7
    const int wm = w >> 2, wn = w & 3;      // 2 x 4 wave grid
    const int fr = lane & 15, kg = lane >> 4;

    const int bid = blockIdx.x;             // 256 blocks -> XCD swizzle
    const int swz = (bid & 7) * 32 + (bid >> 3);
    const int bx = swz & 15, by = swz >> 4;
    const int c0 = bx * 256, j0 = by * 256;

    const int cid0 = w * 128 + lane, cid1 = cid0 + 64;
    const int r0 = cid0 >> 3, k0c = cid0 & 7;
    const int r1 = cid1 >> 3, k1c = cid1 & 7;
    const int so0 = r0 * K + ((k0c ^ (r0 & 7)) << 3);   // ushort units
    const int so1 = r1 * K + ((k1c ^ (r1 & 7)) << 3);
    const int lb0 = (w * 2 + 0) * 512;                  // ushort units
    const int lb1 = (w * 2 + 1) * 512;

    const unsigned short* Aj = A + (size_t)j0 * K;
    const unsigned short* Bc = Bt + (size_t)c0 * K;

#define STAGE_A(buf, half, kt) do { \
    const unsigned short* g_ = Aj + (size_t)((half) * 128) * K + (kt); \
    gload16(g_ + so0, &As[buf][(half) * 8192 + lb0]); \
    gload16(g_ + so1, &As[buf][(half) * 8192 + lb1]); } while (0)
#define STAGE_B(buf, half, kt) do { \
    const unsigned short* g_ = Bc + (size_t)((half) * 128) * K + (kt); \
    gload16(g_ + so0, &Bs[buf][(half) * 8192 + lb0]); \
    gload16(g_ + so1, &Bs[buf][(half) * 8192 + lb1]); } while (0)

    // prologue: tile0 complete (8) + tile1 {Ah0, Ah1, Bh0} (6)
    STAGE_A(0, 0, 0);  STAGE_A(0, 1, 0);
    STAGE_B(0, 0, 0);  STAGE_B(0, 1, 0);
    STAGE_A(1, 0, 64); STAGE_A(1, 1, 64);
    STAGE_B(1, 0, 64);
    asm volatile("s_waitcnt vmcnt(6)" ::: "memory");   // tile0's 8 landed
    bar();

    const int x0 = ((kg) ^ (fr & 7)) << 4;        // ks0 chunk, bytes
    const int x1 = ((4 + kg) ^ (fr & 7)) << 4;    // ks1 chunk, bytes
    int aOff[8], bOff[4];
    #pragma unroll
    for (int m = 0; m < 8; m++) aOff[m] = (wm * 128 + m * 16 + fr) * 128;
    #pragma unroll
    for (int n = 0; n < 4; n++) bOff[n] = (wn * 64 + n * 16 + fr) * 128;

    // read-ahead tile0's ks0-lo A frags + ks0 B frags
    s16x8 af0c[4], bf0c[4];
    #pragma unroll
    for (int m = 0; m < 4; m++) af0c[m] = *(const s16x8*)((const char*)As[0] + aOff[m] + x0);
    #pragma unroll
    for (int n = 0; n < 4; n++) bf0c[n] = *(const s16x8*)((const char*)Bs[0] + bOff[n] + x0);

    f32x4 acc[8][4] = {};

    for (int t = 0; t < NT; t++) {
        const int P = t & 1;
        const char* Ap = (const char*)As[P];
        const char* Bp = (const char*)Bs[P];
        const char* Aq = (const char*)As[P ^ 1];
        const char* Bq = (const char*)Bs[P ^ 1];
        const int kt1 = (t + 1) * 64, kt2 = (t + 2) * 64;
        const bool s1 = (t + 1) < NT, s2 = (t + 2) < NT;
        s16x8 af0h[4], af1l[4], af1h[4], bf1[4], af0n[4], bf0n[4];

        // ---- phase A
        #pragma unroll
        for (int m = 0; m < 4; m++) af0h[m] = *(const s16x8*)(Ap + aOff[m + 4] + x0);
        #pragma unroll
        for (int m = 0; m < 4; m++) af1l[m] = *(const s16x8*)(Ap + aOff[m] + x1);
        if (s1) STAGE_B(P ^ 1, 1, kt1);
        __builtin_amdgcn_s_setprio(1);
        #pragma unroll
        for (int m = 0; m < 4; m++)
            #pragma unroll
            for (int n = 0; n < 4; n++)
                acc[m][n] = __builtin_amdgcn_mfma_f32_16x16x32_bf16(af0c[m], bf0c[n], acc[m][n], 0, 0, 0);
        __builtin_amdgcn_s_setprio(0);

        // ---- phase B
        #pragma unroll
        for (int m = 0; m < 4; m++) af1h[m] = *(const s16x8*)(Ap + aOff[m + 4] + x1);
        #pragma unroll
        for (int n = 0; n < 4; n++) bf1[n] = *(const s16x8*)(Bp + bOff[n] + x1);
        __builtin_amdgcn_s_setprio(1);
        #pragma unroll
        for (int m = 4; m < 8; m++)
            #pragma unroll
            for (int n = 0; n < 4; n++)
                acc[m][n] = __builtin_amdgcn_mfma_f32_16x16x32_bf16(af0h[m - 4], bf0c[n], acc[m][n], 0, 0, 0);
        __builtin_amdgcn_s_setprio(0);
        asm volatile("s_waitcnt lgkmcnt(0)" ::: "memory");
        bar();                                   // BAR(i)

        // ---- phase C
        __builtin_amdgcn_s_setprio(1);
        #pragma unroll
        for (int m = 0; m < 4; m++)
            #pragma unroll
            for (int n = 0; n < 4; n++)
                acc[m][n] = __builtin_amdgcn_mfma_f32_16x16x32_bf16(af1l[m], bf1[n], acc[m][n], 0, 0, 0);
        __builtin_amdgcn_s_setprio(0);
        if (s2) {
            STAGE_A(P, 0, kt2);
            STAGE_A(P, 1, kt2);
            STAGE_B(P, 0, kt2);
            asm volatile("s_waitcnt vmcnt(6)" ::: "memory");
        } else {
            asm volatile("s_waitcnt vmcnt(0)" ::: "memory");
        }
        bar();                                   // BAR(ii)

        // ---- phase D
        if (s1) {
            #pragma unroll
            for (int m = 0; m < 4; m++) af0n[m] = *(const s16x8*)(Aq + aOff[m] + x0);
            #pragma unroll
            for (int n = 0; n < 4; n++) bf0n[n] = *(const s16x8*)(Bq + bOff[n] + x0);
        }
        __builtin_amdgcn_s_setprio(1);
        #pragma unroll
        for (int m = 4; m < 8; m++)
            #pragma unroll
            for (int n = 0; n < 4; n++)
                acc[m][n] = __builtin_amdgcn_mfma_f32_16x16x32_bf16(af1h[m - 4], bf1[n], acc[m][n], 0, 0, 0);
        __builtin_amdgcn_s_setprio(0);
        if (s1) {
            #pragma unroll
            for (int m = 0; m < 4; m++) af0c[m] = af0n[m];
            #pragma unroll
            for (int n = 0; n < 4; n++) bf0c[n] = bf0n[n];
        }
    }
#undef STAGE_A
#undef STAGE_B

    // epilogue
    #pragma unroll
    for (int m = 0; m < 8; m++) {
        int rbase = j0 + wm * 128 + m * 16 + kg * 4;
        float dv[4];
        #pragma unroll
        for (int r = 0; r < 4; r++) dv[r] = dinv[rbase + r];
        #pragma unroll
        for (int n = 0; n < 4; n++) {
            int gcol = c0 + wn * 64 + n * 16 + fr;
            float bb = bias[gcol & (DH - 1)];
            #pragma unroll
            for (int r = 0; r < 4; r++) {
                float v = acc[m][n][r] * dv[r] + bb;
                v = v > 0.f ? v : 0.f;
                H[(size_t)(rbase + r) * NN + gcol] = f2bf(v);
            }
        }
    }
}

// ---------- k_z2: MFMA-based ZT = dinv_j * (H_b @ W2), per block: 128 j x one batch ----------
// H layout: [j][c = b*128 + f], row stride NN.  ZT[b*32+g][j] bf16.
__global__ __launch_bounds__(256) void k_z2(
    const unsigned short* __restrict__ H, const float* __restrict__ W2,
    const float* __restrict__ dinv, unsigned short* __restrict__ ZT)
{
    __shared__ __align__(16) unsigned short Hs[128 * DH];     // 32 KB, [j][f] linear
    __shared__ __align__(16) unsigned short W2Ts[DOUT * DH];  // 8 KB, [g][f]
    const int tid = threadIdx.x;
    const int j0 = blockIdx.x * 128, b = blockIdx.y;
    const unsigned short* Hb = H + (size_t)j0 * NN + b * DH;

    // stage H tile: 2048 chunks of 16B, linear LDS = linear source
    #pragma unroll
    for (int q = 0; q < 8; q++) {
        int cid = q * 256 + tid;
        int row = cid >> 4, kc = cid & 15;
        gload16(Hb + (size_t)row * NN + kc * 8, &Hs[cid * 8]);
    }
    // stage W2^T bf16: 4096 elems
    #pragma unroll
    for (int q = 0; q < 16; q++) {
        int idx = q * 256 + tid;
        int f = idx >> 5, g = idx & 31;
        W2Ts[g * DH + f] = f2bf(W2[f * DOUT + g]);
    }
    __syncthreads();   // full vmcnt/lgkm drain

    const int lane = tid & 63, w = tid >> 6;
    const int fr = lane & 15, kg = lane >> 4;
    f32x4 acc[2][2] = {};
    #pragma unroll
    for (int ks = 0; ks < 4; ks++) {
        s16x8 af[2], bf[2];
        #pragma unroll
        for (int mt = 0; mt < 2; mt++) {
            int row = w * 32 + mt * 16 + fr;
            af[mt] = *(const s16x8*)&Hs[row * DH + ks * 32 + kg * 8];
        }
        #pragma unroll
        for (int nt = 0; nt < 2; nt++) {
            int g = nt * 16 + fr;
            bf[nt] = *(const s16x8*)&W2Ts[g * DH + ks * 32 + kg * 8];
        }
        #pragma unroll
        for (int mt = 0; mt < 2; mt++)
            #pragma unroll
            for (int nt = 0; nt < 2; nt++)
                acc[mt][nt] = __builtin_amdgcn_mfma_f32_16x16x32_bf16(af[mt], bf[nt], acc[mt][nt], 0, 0, 0);
    }
    // epilogue: C row=(lane>>4)*4+r (j), col=lane&15 (g); ZT[b*32+g][j] *= dinv_j
    #pragma unroll
    for (int mt = 0; mt < 2; mt++) {
        int jbase = j0 + w * 32 + mt * 16 + kg * 4;
        float dv[4];
        #pragma unroll
        for (int r = 0; r < 4; r++) dv[r] = dinv[jbase + r];
        #pragma unroll
        for (int nt = 0; nt < 2; nt++) {
            int g = nt * 16 + fr;
            s16x4 pk;
            #pragma unroll
            for (int r = 0; r < 4; r++)
                pk[r] = (short)f2bf(acc[mt][nt][r] * dv[r]);
            *(s16x4*)(ZT + (size_t)(b * DOUT + g) * NN + jbase) = pk;
        }
    }
}

// ---------- gemm2: 64x128 tile (2 blocks/CU) with FUSED softmax epilogue ----------
__global__ __launch_bounds__(256) void gemm_sm(
    const unsigned short* __restrict__ A, const unsigned short* __restrict__ Bt,
    float* __restrict__ out, const float* __restrict__ dinv,
    const float* __restrict__ bias, int K)
{
    constexpr int BK = 64;
    __shared__ __align__(16) unsigned short Asm[64 * BK];    // 8 KB
    __shared__ __align__(16) unsigned short Bsm[128 * BK];   // 16 KB
    const int tid = threadIdx.x;
    const int lane = tid & 63;
    const int w = tid >> 6;
    const int wm = w >> 1, wn = w & 1;     // 2 x 2 wave grid; per-wave 32 x 64
    const int c0 = blockIdx.x * 128;
    const int j0 = blockIdx.y * 64;

    int srcA[2], srcB[4];
    #pragma unroll
    for (int q = 0; q < 2; q++) {
        int cid = q * 256 + tid;           // 0..511
        int row = cid >> 3, kc = cid & 7;
        srcA[q] = row * K + ((kc ^ (row & 7)) << 3);
    }
    #pragma unroll
    for (int q = 0; q < 4; q++) {
        int cid = q * 256 + tid;           // 0..1023
        int row = cid >> 3, kc = cid & 7;
        srcB[q] = row * K + ((kc ^ (row & 7)) << 3);
    }
    const int fr = lane & 15;
    const int kg = lane >> 4;

    f32x4 acc[2][4] = {};
    const unsigned short* Abase = A + (size_t)j0 * K;
    const unsigned short* Bbase = Bt + (size_t)c0 * K;

    for (int kt = 0; kt < K; kt += BK) {
        __syncthreads();
        const unsigned short* Ag = Abase + kt;
        const unsigned short* Bg = Bbase + kt;
        #pragma unroll
        for (int q = 0; q < 2; q++)
            gload16(Ag + srcA[q], &Asm[(q * 256 + tid) * 8]);
        #pragma unroll
        for (int q = 0; q < 4; q++)
            gload16(Bg + srcB[q], &Bsm[(q * 256 + tid) * 8]);
        __syncthreads();

        s16x8 af[2][2], bf[2][4];
        #pragma unroll
        for (int ks = 0; ks < 2; ks++) {
            int kc = ks * 4 + kg;
            #pragma unroll
            for (int m = 0; m < 2; m++) {
                int row = wm * 32 + m * 16 + fr;
                af[ks][m] = *(const s16x8*)((const char*)Asm + row * 128 + ((kc ^ (row & 7)) << 4));
            }
            #pragma unroll
            for (int n = 0; n < 4; n++) {
                int row = wn * 64 + n * 16 + fr;
                bf[ks][n] = *(const s16x8*)((const char*)Bsm + row * 128 + ((kc ^ (row & 7)) << 4));
            }
        }
        #pragma unroll
        for (int ks = 0; ks < 2; ks++)
            #pragma unroll
            for (int m = 0; m < 2; m++)
                #pragma unroll
                for (int n = 0; n < 4; n++)
                    acc[m][n] = __builtin_amdgcn_mfma_f32_16x16x32_bf16(
                        af[ks][m], bf[ks][n], acc[m][n], 0, 0, 0);
    }

    // fused epilogue: g = fr (n even) / fr+16 (n odd); batch = (c0>>5) + wn*2 + (n>>1)
    const float b_lo = bias[fr], b_hi = bias[fr + 16];
    #pragma unroll
    for (int m = 0; m < 2; m++) {
        int rbase = j0 + wm * 32 + m * 16 + kg * 4;
        float dv[4];
        #pragma unroll
        for (int r = 0; r < 4; r++) dv[r] = dinv[rbase + r];
        #pragma unroll
        for (int np = 0; np < 2; np++) {
            int bg = (c0 >> 5) + wn * 2 + np;       // batch index 0..31
            #pragma unroll
            for (int r = 0; r < 4; r++) {
                int row = rbase + r;                 // node j
                float v0 = acc[m][np * 2][r]     * dv[r] + b_lo;   // g = fr
                float v1 = acc[m][np * 2 + 1][r] * dv[r] + b_hi;   // g = fr+16
                float mx = fmaxf(v0, v1);
                #pragma unroll
                for (int d = 8; d; d >>= 1) mx = fmaxf(mx, __shfl_xor(mx, d));
                float e0 = expf(v0 - mx), e1 = expf(v1 - mx);
                float s = e0 + e1;
                #pragma unroll
                for (int d = 8; d; d >>= 1) s += __shfl_xor(s, d);
                float inv = 1.0f / s;
                size_t ob = ((size_t)bg * NN + row) * DOUT;
                out[ob + fr]      = e0 * inv;
                out[ob + fr + 16] = e1 * inv;
            }
        }
    }
}

extern "C" void kernel_launch(void* const* d_in, const int* in_sizes, int n_in,
                              void* d_out, int out_size, void* d_ws, size_t ws_size,
                              hipStream_t stream)
{
    (void)in_sizes; (void)n_in; (void)out_size; (void)ws_size;
    const float* x    = (const float*)d_in[0];
    const float* emb1 = (const float*)d_in[1];
    const float* emb2 = (const float*)d_in[2];
    const float* l1w  = (const float*)d_in[3];
    const float* l1b  = (const float*)d_in[4];
    const float* l2w  = (const float*)d_in[5];
    const float* l2b  = (const float*)d_in[6];
    const float* g1w  = (const float*)d_in[7];
    const float* g1b  = (const float*)d_in[8];
    const float* g2w  = (const float*)d_in[9];
    const float* g2b  = (const float*)d_in[10];
    float* out = (float*)d_out;

    char* w = (char*)d_ws;
    float* n1 = (float*)w;                    w += NN * DIM * 4;
    float* n2 = (float*)w;                    w += NN * DIM * 4;
    int* deg = (int*)w;                       w += NN * 4;
    float* dinv = (float*)w;                  w += NN * 4;
    unsigned short* MT = (unsigned short*)w;  w += (size_t)NN * NN * 2;
    unsigned short* YT = (unsigned short*)w;  w += (size_t)NN * NN * 2;
    unsigned short* H  = (unsigned short*)w;  w += (size_t)NN * NN * 2;
    unsigned short* ZT = (unsigned short*)w;  w += (size_t)(NB * DOUT) * NN * 2;
    // Ux/Vx live in YT's region (dead until k_y1, which runs after gemm_adj)
    unsigned short* Ux = YT;
    unsigned short* Vx = YT + (size_t)NN * KADJ;

    hipMemsetAsync(deg, 0, NN * sizeof(int), stream);
    k_embed<<<1280, 256, 0, stream>>>(emb1, emb2, l1w, l1b, l2w, l2b, n1, n2);
    k_build_uv<<<256, 256, 0, stream>>>(n1, n2, Ux, Vx);
    gemm_adj<<<dim3(32, 32), 256, 0, stream>>>(Vx, Ux, MT, deg);
    k_dinv<<<16, 256, 0, stream>>>(deg, dinv);
    k_y1<<<dim3(32, 32), 256, 0, stream>>>(x, g1w, dinv, YT);
    gemm8<<<256, 512, 0, stream>>>(MT, YT, H, dinv, g1b);
    k_z2<<<dim3(32, 32), 256, 0, stream>>>(H, g2w, dinv, ZT);
    gemm_sm<<<dim3(8, 64), 256, 0, stream>>>(MT, ZT, out, dinv, g2b, NN);
}